// Round 3
// baseline (1009.337 us; speedup 1.0000x reference)
//
#include <hip/hip_runtime.h>

typedef unsigned short ushort_t;
typedef unsigned int uint_t;

#define NB 4
#define NC 128
#define NH 128
#define NW 128
#define NPIX 65536   // NB*NH*NW
#define NMID 32
#define NKK 49
#define NK 392
#define NO 256
#define LN_EPS 1e-6f

__device__ __forceinline__ float bf2f(ushort_t u) {
    union { uint_t i; float f; } v; v.i = ((uint_t)u) << 16; return v.f;
}
__device__ __forceinline__ float asfloat_u(uint_t u) {
    union { uint_t i; float f; } v; v.i = u; return v.f;
}
__device__ __forceinline__ ushort_t f2bf(float f) {
    union { float f; uint_t i; } v; v.f = f;
    uint_t x = v.i;
    uint_t r = (x + 0x7FFFu + ((x >> 16) & 1u)) >> 16;
    return (ushort_t)r;
}
__device__ __forceinline__ float gelu_f(float x) {
    return 0.5f * x * (1.0f + erff(x * 0.70710678118654752f));
}
// dtype-dispatched input load: isf32 ? fp32 : bf16
__device__ __forceinline__ float ldin(const void* p, int i, int isf32) {
    return isf32 ? ((const float*)p)[i] : bf2f(((const ushort_t*)p)[i]);
}

// ---------------------------------------------------------------------------
// KD: dtype detector. Examines low 16 bits of first 512 words of x.
// bf16 data -> every 16-bit half is a plausible bf16 (exp in [110,135]);
// fp32 data -> low halves are mantissa bits (uniform) -> ~10% plausible.
// flag[0] = 1 if fp32, 0 if bf16.
// ---------------------------------------------------------------------------
__global__ void kdetect(const uint_t* __restrict__ xw, int* __restrict__ flag) {
    if (threadIdx.x == 0) {
        int cnt = 0;
        for (int j = 0; j < 512; j++) {
            uint_t w = xw[j];
            uint_t e = (w >> 7) & 0xffu;      // exponent field of low half
            if (e >= 110u && e <= 135u) cnt++;
        }
        flag[0] = (cnt < 256) ? 1 : 0;
    }
}

// ---------------------------------------------------------------------------
// Sentinel: ws too small -> fill out with 0x40004000 (finite, recognizable).
// ---------------------------------------------------------------------------
__global__ void ksentinel(uint_t* __restrict__ out, int nwords) {
    int i = blockIdx.x * 256 + threadIdx.x;
    if (i < nwords) out[i] = 0x40004000u;
}

// ---------------------------------------------------------------------------
// K0a: transpose x (B,C,H,W) -> xT (B,H,W,C) canonical bf16.
// grid (8, 128, 4); block 256.
// ---------------------------------------------------------------------------
__global__ __launch_bounds__(256) void ktrans(const void* __restrict__ x,
                                              ushort_t* __restrict__ xT,
                                              const int* __restrict__ flag) {
    int isf32 = flag[0];
    int b = blockIdx.z, h = blockIdx.y;
    int wchunk = blockIdx.x & 1, cchunk = blockIdx.x >> 1;
    int w0 = wchunk << 6, c0 = cchunk << 5;
    __shared__ ushort_t tile[32][66];
    int tx = threadIdx.x & 63, ty = threadIdx.x >> 6;   // ty in [0,4)
    for (int r = 0; r < 32; r += 4) {
        int idx = (((b * NC + c0 + r + ty) * NH) + h) * NW + w0 + tx;
        tile[r + ty][tx] = isf32 ? f2bf(((const float*)x)[idx])
                                 : ((const ushort_t*)x)[idx];
    }
    __syncthreads();
    int cc = threadIdx.x & 31, wq = threadIdx.x >> 5;   // wq in [0,8)
    for (int pp = 0; pp < 64; pp += 8) {
        int wx = pp + wq;
        xT[((size_t)((b * NH + h) * NW) + w0 + wx) * NC + c0 + cc] = tile[cc][wx];
    }
}

// ---------------------------------------------------------------------------
// K0b: param prep -> canonical fp32. grid 128 x 256 (32768 threads).
// w1T[c*32+m]=w1[m,c]; w2T[m*392+k]=w2[k,m]; all vectors -> fp32.
// ---------------------------------------------------------------------------
__global__ __launch_bounds__(256) void kprep(const void* w1, const void* w2,
                                             const void* conv_w, const void* map_w,
                                             const void* b1, const void* b2,
                                             const void* ln1w, const void* ln1b,
                                             const void* ln2w, const void* ln2b,
                                             const void* map_b,
                                             const void* ln3w, const void* ln3b,
                                             const int* __restrict__ flag,
                                             float* __restrict__ w1T,
                                             float* __restrict__ w2T,
                                             float* __restrict__ cwf,
                                             float* __restrict__ mwf,
                                             float* __restrict__ b1f,
                                             float* __restrict__ b2f,
                                             float* __restrict__ ln1wf,
                                             float* __restrict__ ln1bf,
                                             float* __restrict__ ln2wf,
                                             float* __restrict__ ln2bf,
                                             float* __restrict__ mbf,
                                             float* __restrict__ ln3wf,
                                             float* __restrict__ ln3bf) {
    int isf32 = flag[0];
    int i = blockIdx.x * 256 + threadIdx.x;
    if (i < NMID * NC) { int m = i >> 7, c = i & 127; w1T[c * NMID + m] = ldin(w1, i, isf32); }
    if (i < NK * NMID) { int k = i >> 5, m = i & 31;  w2T[m * NK + k]   = ldin(w2, i, isf32); }
    cwf[i] = ldin(conv_w, i, isf32);
    mwf[i] = ldin(map_w, i, isf32);
    if (i < NMID) b1f[i] = ldin(b1, i, isf32);
    if (i < NK)   b2f[i] = ldin(b2, i, isf32);
    if (i < NC) { ln1wf[i] = ldin(ln1w, i, isf32); ln1bf[i] = ldin(ln1b, i, isf32); }
    if (i < NO) {
        ln2wf[i] = ldin(ln2w, i, isf32); ln2bf[i] = ldin(ln2b, i, isf32);
        mbf[i]   = ldin(map_b, i, isf32);
        ln3wf[i] = ldin(ln3w, i, isf32); ln3bf[i] = ldin(ln3b, i, isf32);
    }
}

// ---------------------------------------------------------------------------
// K1: fused involution + LN(C=128) + GELU. One block = one pixel, 128 threads.
// ---------------------------------------------------------------------------
__global__ __launch_bounds__(128) void k1(const ushort_t* __restrict__ xT,
                                          const float* __restrict__ w1T,
                                          const float* __restrict__ b1f,
                                          const float* __restrict__ w2T,
                                          const float* __restrict__ b2f,
                                          const float* __restrict__ ln1wf,
                                          const float* __restrict__ ln1bf,
                                          ushort_t* __restrict__ y1) {
    int p = blockIdx.x;
    int h = (p >> 7) & 127;
    int w = p & 127;
    int c = threadIdx.x;

    __shared__ float xpix[NC];
    __shared__ float mid_s[NMID];
    __shared__ float wk_s[NK];
    __shared__ float red1[NC];
    __shared__ float red2[NC];

    xpix[c] = bf2f(xT[(size_t)p * NC + c]);
    __syncthreads();

    if (c < NMID) {
        float s = b1f[c];
        for (int i = 0; i < NC; i++) s = fmaf(w1T[i * NMID + c], xpix[i], s);
        mid_s[c] = fmaxf(s, 0.0f);
    }
    __syncthreads();

    for (int k = c; k < NK; k += 128) {
        float s = b2f[k];
        for (int m = 0; m < NMID; m++) s = fmaf(w2T[m * NK + k], mid_s[m], s);
        wk_s[k] = s;
    }
    __syncthreads();

    int g = c >> 4;
    float acc = 0.0f;
    for (int dy = -3; dy <= 3; dy++) {
        int hh = h + dy;
        if ((unsigned)hh >= (unsigned)NH) continue;
        for (int dx = -3; dx <= 3; dx++) {
            int ww = w + dx;
            if ((unsigned)ww >= (unsigned)NW) continue;
            int pn = p + dy * NW + dx;
            acc = fmaf(wk_s[g * NKK + (dy + 3) * 7 + (dx + 3)],
                       bf2f(xT[(size_t)pn * NC + c]), acc);
        }
    }

    red1[c] = acc;
    red2[c] = acc * acc;
    __syncthreads();
    for (int s = 64; s > 0; s >>= 1) {
        if (c < s) { red1[c] += red1[c + s]; red2[c] += red2[c + s]; }
        __syncthreads();
    }
    float mean = red1[0] * (1.0f / NC);
    float var = red2[0] * (1.0f / NC) - mean * mean;
    float xn = (acc - mean) * rsqrtf(var + LN_EPS);
    float v = ln1wf[c] * xn + ln1bf[c];
    y1[(size_t)p * NC + c] = f2bf(gelu_f(v));
}

// ---------------------------------------------------------------------------
// K23: conv(y1)+LN2, map(x)+LN3, add, GELU -> out (dtype-dispatched store).
// Block 512 = 8 waves; 64 pixels/block (lane=pixel); wave q -> channels
// [q*32, q*32+32). grid 1024.
// ---------------------------------------------------------------------------
__global__ __launch_bounds__(512) void k23(const ushort_t* __restrict__ y1,
                                           const ushort_t* __restrict__ xT,
                                           const float* __restrict__ cwf,
                                           const float* __restrict__ mwf,
                                           const float* __restrict__ mbf,
                                           const float* __restrict__ ln2wf,
                                           const float* __restrict__ ln2bf,
                                           const float* __restrict__ ln3wf,
                                           const float* __restrict__ ln3bf,
                                           void* __restrict__ out,
                                           const int* __restrict__ flag) {
    __shared__ __align__(16) ushort_t ybuf[64 * 132];
    __shared__ __align__(16) ushort_t xbuf[64 * 132];
    __shared__ float sred[8][64][4];
    __shared__ float sstat[64][4];

    int isf32 = flag[0];
    int t = threadIdx.x;
    int P0 = blockIdx.x * 64;

    for (int j = 0; j < 16; j++) {
        int idx = j * 512 + t;          // [0, 8192)
        int px = idx >> 7, cc = idx & 127;
        ybuf[px * 132 + cc] = y1[(size_t)P0 * NC + idx];
        xbuf[px * 132 + cc] = xT[(size_t)P0 * NC + idx];
    }
    __syncthreads();

    int lane = t & 63;
    int q = __builtin_amdgcn_readfirstlane(t >> 6);   // wave id, uniform
    int obase = q << 5;
    const ushort_t* yrow = ybuf + lane * 132;
    const ushort_t* xrow = xbuf + lane * 132;

    float ac[32], am[32];
#pragma unroll
    for (int o = 0; o < 32; o++) { ac[o] = 0.0f; am[o] = 0.0f; }

    for (int cb = 0; cb < 128; cb += 4) {
        uint2 yu = *(const uint2*)(yrow + cb);
        uint2 xu = *(const uint2*)(xrow + cb);
        float yv0 = asfloat_u(yu.x << 16), yv1 = asfloat_u(yu.x & 0xffff0000u);
        float yv2 = asfloat_u(yu.y << 16), yv3 = asfloat_u(yu.y & 0xffff0000u);
        float xv0 = asfloat_u(xu.x << 16), xv1 = asfloat_u(xu.x & 0xffff0000u);
        float xv2 = asfloat_u(xu.y << 16), xv3 = asfloat_u(xu.y & 0xffff0000u);
        const float* cp = cwf + (obase << 7) + cb;
        const float* mp = mwf + (obase << 7) + cb;
#pragma unroll
        for (int o = 0; o < 32; o++) {
            const float* c0 = cp + (o << 7);
            const float* m0 = mp + (o << 7);
            ac[o] = fmaf(c0[0], yv0, ac[o]); ac[o] = fmaf(c0[1], yv1, ac[o]);
            ac[o] = fmaf(c0[2], yv2, ac[o]); ac[o] = fmaf(c0[3], yv3, ac[o]);
            am[o] = fmaf(m0[0], xv0, am[o]); am[o] = fmaf(m0[1], xv1, am[o]);
            am[o] = fmaf(m0[2], xv2, am[o]); am[o] = fmaf(m0[3], xv3, am[o]);
        }
    }

    float s1 = 0.f, s1q = 0.f, s2 = 0.f, s2q = 0.f;
#pragma unroll
    for (int o = 0; o < 32; o++) {
        am[o] += mbf[obase + o];
        s1 += ac[o]; s1q += ac[o] * ac[o];
        s2 += am[o]; s2q += am[o] * am[o];
    }
    sred[q][lane][0] = s1; sred[q][lane][1] = s1q;
    sred[q][lane][2] = s2; sred[q][lane][3] = s2q;
    __syncthreads();

    if (t < 64) {
        float a0 = 0.f, a1 = 0.f, a2 = 0.f, a3 = 0.f;
        for (int r = 0; r < 8; r++) {
            a0 += sred[r][t][0]; a1 += sred[r][t][1];
            a2 += sred[r][t][2]; a3 += sred[r][t][3];
        }
        float m1 = a0 * (1.0f / NO);
        float v1 = a1 * (1.0f / NO) - m1 * m1;
        float m2 = a2 * (1.0f / NO);
        float v2 = a3 * (1.0f / NO) - m2 * m2;
        sstat[t][0] = m1; sstat[t][1] = rsqrtf(v1 + LN_EPS);
        sstat[t][2] = m2; sstat[t][3] = rsqrtf(v2 + LN_EPS);
    }
    __syncthreads();

    float m1 = sstat[lane][0], r1 = sstat[lane][1];
    float m2 = sstat[lane][2], r2 = sstat[lane][3];
    int b = P0 >> 14;
    int plocal = (P0 & 16383) + lane;
#pragma unroll
    for (int o = 0; o < 32; o++) {
        int og = obase + o;
        float v1 = (ac[o] - m1) * r1 * ln2wf[og] + ln2bf[og];
        float v2 = (am[o] - m2) * r2 * ln3wf[og] + ln3bf[og];
        float r = gelu_f(v1 + v2);
        size_t oi = (size_t)(((b * NO + og) << 14) + plocal);
        if (isf32) ((float*)out)[oi] = r;
        else       ((ushort_t*)out)[oi] = f2bf(r);
    }
}

// ---------------------------------------------------------------------------
extern "C" void kernel_launch(void* const* d_in, const int* in_sizes, int n_in,
                              void* d_out, int out_size, void* d_ws, size_t ws_size,
                              hipStream_t stream) {
    const void* x      = d_in[0];
    const void* w1     = d_in[1];
    const void* b1     = d_in[2];
    const void* w2     = d_in[3];
    const void* b2     = d_in[4];
    const void* ln1w   = d_in[5];
    const void* ln1b   = d_in[6];
    const void* conv_w = d_in[7];
    const void* ln2w   = d_in[8];
    const void* ln2b   = d_in[9];
    const void* map_w  = d_in[10];
    const void* map_b  = d_in[11];
    const void* ln3w   = d_in[12];
    const void* ln3b   = d_in[13];

    char* ws = (char*)d_ws;
    ushort_t* xT    = (ushort_t*)(ws);                  // 16,777,216 B
    ushort_t* y1    = (ushort_t*)(ws + 16777216);       // 16,777,216 B
    float*    w1T   = (float*)(ws + 33554432);          //  16,384 B
    float*    w2T   = (float*)(ws + 33570816);          //  50,176 B
    float*    cwf   = (float*)(ws + 33620992);          // 131,072 B
    float*    mwf   = (float*)(ws + 33752064);          // 131,072 B
    float*    b1f   = (float*)(ws + 33883136);          //     128 B
    float*    b2f   = (float*)(ws + 33883264);          //   1,568 B
    float*    ln1wf = (float*)(ws + 33884832);          //     512 B
    float*    ln1bf = (float*)(ws + 33885344);          //     512 B
    float*    mbf   = (float*)(ws + 33885856);          //   1,024 B
    float*    ln2wf = (float*)(ws + 33886880);          //   1,024 B
    float*    ln2bf = (float*)(ws + 33887904);          //   1,024 B
    float*    ln3wf = (float*)(ws + 33888928);          //   1,024 B
    float*    ln3bf = (float*)(ws + 33889952);          //   1,024 B
    int*      flag  = (int*)(ws + 33890976);            //      16 B
    const size_t NEED = 33891328;

    if (ws_size < NEED) {
        // workspace too small: write finite sentinel so the next round's
        // absmax (finite, ~7.4) confirms this diagnosis vs NaN.
        int nwords = out_size / 2;
        ksentinel<<<(nwords + 255) / 256, 256, 0, stream>>>((uint_t*)d_out, nwords);
        return;
    }

    kdetect<<<1, 64, 0, stream>>>((const uint_t*)x, flag);
    kprep<<<128, 256, 0, stream>>>(w1, w2, conv_w, map_w, b1, b2, ln1w, ln1b,
                                   ln2w, ln2b, map_b, ln3w, ln3b, flag,
                                   w1T, w2T, cwf, mwf, b1f, b2f, ln1wf, ln1bf,
                                   ln2wf, ln2bf, mbf, ln3wf, ln3bf);
    ktrans<<<dim3(8, 128, 4), 256, 0, stream>>>(x, xT, flag);
    k1<<<NPIX, 128, 0, stream>>>(xT, w1T, b1f, w2T, b2f, ln1wf, ln1bf, y1);
    k23<<<NPIX / 64, 512, 0, stream>>>(y1, xT, cwf, mwf, mbf,
                                       ln2wf, ln2bf, ln3wf, ln3bf, d_out, flag);
}

// Round 4
// 601.835 us; speedup vs baseline: 1.6771x; 1.6771x over previous
//
#include <hip/hip_runtime.h>

typedef unsigned short ushort_t;
typedef unsigned int uint_t;

#define NB 4
#define NC 128
#define NH 128
#define NW 128
#define NPIX 65536   // NB*NH*NW
#define NMID 32
#define NKK 49
#define NK 392
#define NO 256
#define LN_EPS 1e-6f

typedef __attribute__((ext_vector_type(8))) short short8;
typedef __attribute__((ext_vector_type(4))) float floatx4;

__device__ __forceinline__ float bf2f(ushort_t u) {
    union { uint_t i; float f; } v; v.i = ((uint_t)u) << 16; return v.f;
}
__device__ __forceinline__ ushort_t f2bf(float f) {
    union { float f; uint_t i; } v; v.f = f;
    uint_t x = v.i;
    uint_t r = (x + 0x7FFFu + ((x >> 16) & 1u)) >> 16;
    return (ushort_t)r;
}
__device__ __forceinline__ float gelu_f(float x) {
    return 0.5f * x * (1.0f + erff(x * 0.70710678118654752f));
}
__device__ __forceinline__ float ldin(const void* p, int i, int isf32) {
    return isf32 ? ((const float*)p)[i] : bf2f(((const ushort_t*)p)[i]);
}

// ---------------------------------------------------------------------------
// KD: dtype detector (fp32 vs bf16 input buffers). flag[0]=1 if fp32.
// ---------------------------------------------------------------------------
__global__ void kdetect(const uint_t* __restrict__ xw, int* __restrict__ flag) {
    if (threadIdx.x == 0) {
        int cnt = 0;
        for (int j = 0; j < 512; j++) {
            uint_t w = xw[j];
            uint_t e = (w >> 7) & 0xffu;
            if (e >= 110u && e <= 135u) cnt++;
        }
        flag[0] = (cnt < 256) ? 1 : 0;
    }
}

__global__ void ksentinel(uint_t* __restrict__ out, int nwords) {
    int i = blockIdx.x * 256 + threadIdx.x;
    if (i < nwords) out[i] = 0x40004000u;
}

// ---------------------------------------------------------------------------
// K0a: transpose x (B,C,H,W) -> xT (B,H,W,C) canonical bf16.
// ---------------------------------------------------------------------------
__global__ __launch_bounds__(256) void ktrans(const void* __restrict__ x,
                                              ushort_t* __restrict__ xT,
                                              const int* __restrict__ flag) {
    int isf32 = flag[0];
    int b = blockIdx.z, h = blockIdx.y;
    int wchunk = blockIdx.x & 1, cchunk = blockIdx.x >> 1;
    int w0 = wchunk << 6, c0 = cchunk << 5;
    __shared__ ushort_t tile[32][66];
    int tx = threadIdx.x & 63, ty = threadIdx.x >> 6;
    for (int r = 0; r < 32; r += 4) {
        int idx = (((b * NC + c0 + r + ty) * NH) + h) * NW + w0 + tx;
        tile[r + ty][tx] = isf32 ? f2bf(((const float*)x)[idx])
                                 : ((const ushort_t*)x)[idx];
    }
    __syncthreads();
    int cc = threadIdx.x & 31, wq = threadIdx.x >> 5;
    for (int pp = 0; pp < 64; pp += 8) {
        int wx = pp + wq;
        xT[((size_t)((b * NH + h) * NW) + w0 + wx) * NC + c0 + cc] = tile[cc][wx];
    }
}

// ---------------------------------------------------------------------------
// K0b: param prep. w1T/w2T fp32 (k1), wcb/wmb bf16 row-major [o][c] (k23 MFMA),
// small vectors -> fp32.
// ---------------------------------------------------------------------------
__global__ __launch_bounds__(256) void kprep(const void* w1, const void* w2,
                                             const void* conv_w, const void* map_w,
                                             const void* b1, const void* b2,
                                             const void* ln1w, const void* ln1b,
                                             const void* ln2w, const void* ln2b,
                                             const void* map_b,
                                             const void* ln3w, const void* ln3b,
                                             const int* __restrict__ flag,
                                             float* __restrict__ w1T,
                                             float* __restrict__ w2T,
                                             ushort_t* __restrict__ wcb,
                                             ushort_t* __restrict__ wmb,
                                             float* __restrict__ b1f,
                                             float* __restrict__ b2f,
                                             float* __restrict__ ln1wf,
                                             float* __restrict__ ln1bf,
                                             float* __restrict__ ln2wf,
                                             float* __restrict__ ln2bf,
                                             float* __restrict__ mbf,
                                             float* __restrict__ ln3wf,
                                             float* __restrict__ ln3bf) {
    int isf32 = flag[0];
    int i = blockIdx.x * 256 + threadIdx.x;
    if (i < NMID * NC) { int m = i >> 7, c = i & 127; w1T[c * NMID + m] = ldin(w1, i, isf32); }
    if (i < NK * NMID) { int k = i >> 5, m = i & 31;  w2T[m * NK + k]   = ldin(w2, i, isf32); }
    wcb[i] = f2bf(ldin(conv_w, i, isf32));
    wmb[i] = f2bf(ldin(map_w, i, isf32));
    if (i < NMID) b1f[i] = ldin(b1, i, isf32);
    if (i < NK)   b2f[i] = ldin(b2, i, isf32);
    if (i < NC) { ln1wf[i] = ldin(ln1w, i, isf32); ln1bf[i] = ldin(ln1b, i, isf32); }
    if (i < NO) {
        ln2wf[i] = ldin(ln2w, i, isf32); ln2bf[i] = ldin(ln2b, i, isf32);
        mbf[i]   = ldin(map_b, i, isf32);
        ln3wf[i] = ldin(ln3w, i, isf32); ln3bf[i] = ldin(ln3b, i, isf32);
    }
}

// ---------------------------------------------------------------------------
// K1: fused involution + LN(C=128) + GELU. One block = one pixel, 128 threads.
// (unchanged this round; next optimization target)
// ---------------------------------------------------------------------------
__global__ __launch_bounds__(128) void k1(const ushort_t* __restrict__ xT,
                                          const float* __restrict__ w1T,
                                          const float* __restrict__ b1f,
                                          const float* __restrict__ w2T,
                                          const float* __restrict__ b2f,
                                          const float* __restrict__ ln1wf,
                                          const float* __restrict__ ln1bf,
                                          ushort_t* __restrict__ y1) {
    int p = blockIdx.x;
    int h = (p >> 7) & 127;
    int w = p & 127;
    int c = threadIdx.x;

    __shared__ float xpix[NC];
    __shared__ float mid_s[NMID];
    __shared__ float wk_s[NK];
    __shared__ float red1[NC];
    __shared__ float red2[NC];

    xpix[c] = bf2f(xT[(size_t)p * NC + c]);
    __syncthreads();

    if (c < NMID) {
        float s = b1f[c];
        for (int i = 0; i < NC; i++) s = fmaf(w1T[i * NMID + c], xpix[i], s);
        mid_s[c] = fmaxf(s, 0.0f);
    }
    __syncthreads();

    for (int k = c; k < NK; k += 128) {
        float s = b2f[k];
        for (int m = 0; m < NMID; m++) s = fmaf(w2T[m * NK + k], mid_s[m], s);
        wk_s[k] = s;
    }
    __syncthreads();

    int g = c >> 4;
    float acc = 0.0f;
    for (int dy = -3; dy <= 3; dy++) {
        int hh = h + dy;
        if ((unsigned)hh >= (unsigned)NH) continue;
        for (int dx = -3; dx <= 3; dx++) {
            int ww = w + dx;
            if ((unsigned)ww >= (unsigned)NW) continue;
            int pn = p + dy * NW + dx;
            acc = fmaf(wk_s[g * NKK + (dy + 3) * 7 + (dx + 3)],
                       bf2f(xT[(size_t)pn * NC + c]), acc);
        }
    }

    red1[c] = acc;
    red2[c] = acc * acc;
    __syncthreads();
    for (int s = 64; s > 0; s >>= 1) {
        if (c < s) { red1[c] += red1[c + s]; red2[c] += red2[c + s]; }
        __syncthreads();
    }
    float mean = red1[0] * (1.0f / NC);
    float var = red2[0] * (1.0f / NC) - mean * mean;
    float xn = (acc - mean) * rsqrtf(var + LN_EPS);
    float v = ln1wf[c] * xn + ln1bf[c];
    y1[(size_t)p * NC + c] = f2bf(gelu_f(v));
}

// ---------------------------------------------------------------------------
// K23 (MFMA): conv(y1)+LN2, map(x)+LN3, add, GELU -> out.
// Block = 256 thr = 4 waves; 32 pixels x 256 outputs x both branches.
// mfma_f32_16x16x32_bf16; A staged in LDS in fragment order; B from global.
// Wave w owns output cols [w*64, w*64+64) (4 Ntiles of 16).
// grid 2048.
// ---------------------------------------------------------------------------
__global__ __launch_bounds__(256) void k23(const ushort_t* __restrict__ y1,
                                           const ushort_t* __restrict__ xT,
                                           const ushort_t* __restrict__ wcb,
                                           const ushort_t* __restrict__ wmb,
                                           const float* __restrict__ mbf,
                                           const float* __restrict__ ln2wf,
                                           const float* __restrict__ ln2bf,
                                           const float* __restrict__ ln3wf,
                                           const float* __restrict__ ln3bf,
                                           void* __restrict__ out,
                                           const int* __restrict__ flag) {
    // smem: [0,8K) ybufF | [8K,16K) xbufF  -- reused as obuf [0,33792*4)
    //       [135168, +2048) sred | [137216, +512) sstat
    __shared__ __align__(16) char smem[135168 + 2048 + 512];
    ushort_t* ybufF = (ushort_t*)smem;               // 512 chunks of 16 B
    ushort_t* xbufF = (ushort_t*)(smem + 8192);
    float*    obuf  = (float*)smem;                  // [256][33] f32
    float*    sred  = (float*)(smem + 135168);       // [4][32][4]
    float*    sstat = (float*)(smem + 137216);       // [32][4]

    int isf32 = flag[0];
    int t = threadIdx.x;
    int P0 = blockIdx.x * 32;

    // --- stage A tiles (y and x) into fragment-ordered LDS -----------------
    // chunk q in [0,512): pl=q&15, quad=(q>>4)&3, kb=(q>>6)&3, mt=(q>>8)&1
    // content: Y[P0 + mt*16+pl][kb*32+quad*8 .. +8] -> chunk (mt*4+kb)*64+quad*16+pl
    for (int rep = 0; rep < 2; rep++) {
        int q = rep * 256 + t;
        int pl = q & 15, quad = (q >> 4) & 3, kb = (q >> 6) & 3, mt = (q >> 8) & 1;
        int p = mt * 16 + pl;
        int c0 = kb * 32 + quad * 8;
        size_t src = (size_t)(P0 + p) * NC + c0;
        int dst = ((mt * 4 + kb) * 64 + quad * 16 + pl) * 8;
        *(uint4*)&ybufF[dst] = *(const uint4*)&y1[src];
        *(uint4*)&xbufF[dst] = *(const uint4*)&xT[src];
    }
    __syncthreads();

    int lane = t & 63;
    int w = __builtin_amdgcn_readfirstlane(t >> 6);  // wave id 0..3
    int quad = lane >> 4;
    int l16 = lane & 15;

    floatx4 accC[2][4], accM[2][4];
#pragma unroll
    for (int mt = 0; mt < 2; mt++)
#pragma unroll
        for (int nt = 0; nt < 4; nt++) {
            accC[mt][nt] = (floatx4)0.0f;
            accM[mt][nt] = (floatx4)0.0f;
        }

    // --- K loop: 4 kb steps of K=32, 16 MFMAs each -------------------------
#pragma unroll
    for (int kb = 0; kb < 4; kb++) {
        short8 aY0 = *(const short8*)&ybufF[((0 * 4 + kb) * 64 + lane) * 8];
        short8 aY1 = *(const short8*)&ybufF[((1 * 4 + kb) * 64 + lane) * 8];
        short8 aX0 = *(const short8*)&xbufF[((0 * 4 + kb) * 64 + lane) * 8];
        short8 aX1 = *(const short8*)&xbufF[((1 * 4 + kb) * 64 + lane) * 8];
#pragma unroll
        for (int nt = 0; nt < 4; nt++) {
            int o = w * 64 + nt * 16 + l16;
            size_t boff = (size_t)o * NC + kb * 32 + quad * 8;
            short8 bc = *(const short8*)&wcb[boff];
            short8 bm = *(const short8*)&wmb[boff];
            accC[0][nt] = __builtin_amdgcn_mfma_f32_16x16x32_bf16(aY0, bc, accC[0][nt], 0, 0, 0);
            accC[1][nt] = __builtin_amdgcn_mfma_f32_16x16x32_bf16(aY1, bc, accC[1][nt], 0, 0, 0);
            accM[0][nt] = __builtin_amdgcn_mfma_f32_16x16x32_bf16(aX0, bm, accM[0][nt], 0, 0, 0);
            accM[1][nt] = __builtin_amdgcn_mfma_f32_16x16x32_bf16(aX1, bm, accM[1][nt], 0, 0, 0);
        }
    }

    // --- map bias + per-lane LN coefficients -------------------------------
    float mb_[4], l2w_[4], l2b_[4], l3w_[4], l3b_[4];
#pragma unroll
    for (int nt = 0; nt < 4; nt++) {
        int o = w * 64 + nt * 16 + l16;
        mb_[nt] = mbf[o];
        l2w_[nt] = ln2wf[o]; l2b_[nt] = ln2bf[o];
        l3w_[nt] = ln3wf[o]; l3b_[nt] = ln3bf[o];
    }
#pragma unroll
    for (int mt = 0; mt < 2; mt++)
#pragma unroll
        for (int nt = 0; nt < 4; nt++)
#pragma unroll
            for (int r = 0; r < 4; r++)
                accM[mt][nt][r] += mb_[nt];

    // --- LN partial sums: per (mt,reg) pixel row, butterfly over 16 n-lanes -
#pragma unroll
    for (int mt = 0; mt < 2; mt++) {
#pragma unroll
        for (int r = 0; r < 4; r++) {
            float s1 = 0.f, s1q = 0.f, s2 = 0.f, s2q = 0.f;
#pragma unroll
            for (int nt = 0; nt < 4; nt++) {
                float a = accC[mt][nt][r], m = accM[mt][nt][r];
                s1 += a; s1q += a * a; s2 += m; s2q += m * m;
            }
#pragma unroll
            for (int d = 1; d < 16; d <<= 1) {
                s1  += __shfl_xor(s1, d);
                s1q += __shfl_xor(s1q, d);
                s2  += __shfl_xor(s2, d);
                s2q += __shfl_xor(s2q, d);
            }
            if (l16 == 0) {
                int px = mt * 16 + quad * 4 + r;
                float* sp = sred + ((w * 32 + px) * 4);
                sp[0] = s1; sp[1] = s1q; sp[2] = s2; sp[3] = s2q;
            }
        }
    }
    __syncthreads();   // also guarantees all A-tile LDS reads are done

    if (t < 32) {
        float a0 = 0.f, a1 = 0.f, a2 = 0.f, a3 = 0.f;
        for (int ww = 0; ww < 4; ww++) {
            const float* sp = sred + ((ww * 32 + t) * 4);
            a0 += sp[0]; a1 += sp[1]; a2 += sp[2]; a3 += sp[3];
        }
        float m1 = a0 * (1.0f / NO);
        float v1 = a1 * (1.0f / NO) - m1 * m1;
        float m2 = a2 * (1.0f / NO);
        float v2 = a3 * (1.0f / NO) - m2 * m2;
        float* st = sstat + t * 4;
        st[0] = m1; st[1] = rsqrtf(v1 + LN_EPS);
        st[2] = m2; st[3] = rsqrtf(v2 + LN_EPS);
    }
    __syncthreads();

    // --- normalize + combine + gelu -> obuf[o][px] (A region now dead) -----
#pragma unroll
    for (int mt = 0; mt < 2; mt++) {
#pragma unroll
        for (int r = 0; r < 4; r++) {
            int px = mt * 16 + quad * 4 + r;
            const float* st = sstat + px * 4;
            float m1 = st[0], r1 = st[1], m2 = st[2], r2 = st[3];
#pragma unroll
            for (int nt = 0; nt < 4; nt++) {
                int o = w * 64 + nt * 16 + l16;
                float v1 = (accC[mt][nt][r] - m1) * r1 * l2w_[nt] + l2b_[nt];
                float v2 = (accM[mt][nt][r] - m2) * r2 * l3w_[nt] + l3b_[nt];
                obuf[o * 33 + px] = gelu_f(v1 + v2);
            }
        }
    }
    __syncthreads();

    // --- coalesced store: out[(batch*NO+o)*16384 + plocal0 + px] -----------
    int batch = P0 >> 14;
    int plocal0 = P0 & 16383;
    for (int it = 0; it < 32; it++) {
        int idx = it * 256 + t;
        int o = idx >> 5, px = idx & 31;
        float val = obuf[o * 33 + px];
        size_t oi = ((size_t)(batch * NO + o) << 14) + plocal0 + px;
        if (isf32) ((float*)out)[oi] = val;
        else       ((ushort_t*)out)[oi] = f2bf(val);
    }
}

// ---------------------------------------------------------------------------
extern "C" void kernel_launch(void* const* d_in, const int* in_sizes, int n_in,
                              void* d_out, int out_size, void* d_ws, size_t ws_size,
                              hipStream_t stream) {
    const void* x      = d_in[0];
    const void* w1     = d_in[1];
    const void* b1     = d_in[2];
    const void* w2     = d_in[3];
    const void* b2     = d_in[4];
    const void* ln1w   = d_in[5];
    const void* ln1b   = d_in[6];
    const void* conv_w = d_in[7];
    const void* ln2w   = d_in[8];
    const void* ln2b   = d_in[9];
    const void* map_w  = d_in[10];
    const void* map_b  = d_in[11];
    const void* ln3w   = d_in[12];
    const void* ln3b   = d_in[13];

    char* ws = (char*)d_ws;
    ushort_t* xT    = (ushort_t*)(ws);                  // 16,777,216 B
    ushort_t* y1    = (ushort_t*)(ws + 16777216);       // 16,777,216 B
    float*    w1T   = (float*)(ws + 33554432);          //  16,384 B
    float*    w2T   = (float*)(ws + 33570816);          //  50,176 B
    ushort_t* wcb   = (ushort_t*)(ws + 33620992);       //  65,536 B
    ushort_t* wmb   = (ushort_t*)(ws + 33686528);       //  65,536 B
    float*    b1f   = (float*)(ws + 33752064);          //     128 B
    float*    b2f   = (float*)(ws + 33752192);          //   1,568 B
    float*    ln1wf = (float*)(ws + 33753760);          //     512 B
    float*    ln1bf = (float*)(ws + 33754272);          //     512 B
    float*    mbf   = (float*)(ws + 33754784);          //   1,024 B
    float*    ln2wf = (float*)(ws + 33755808);          //   1,024 B
    float*    ln2bf = (float*)(ws + 33756832);          //   1,024 B
    float*    ln3wf = (float*)(ws + 33757856);          //   1,024 B
    float*    ln3bf = (float*)(ws + 33758880);          //   1,024 B
    int*      flag  = (int*)(ws + 33759904);            //      16 B
    const size_t NEED = 33759920;

    if (ws_size < NEED) {
        int nwords = out_size / 2;
        ksentinel<<<(nwords + 255) / 256, 256, 0, stream>>>((uint_t*)d_out, nwords);
        return;
    }

    kdetect<<<1, 64, 0, stream>>>((const uint_t*)x, flag);
    kprep<<<128, 256, 0, stream>>>(w1, w2, conv_w, map_w, b1, b2, ln1w, ln1b,
                                   ln2w, ln2b, map_b, ln3w, ln3b, flag,
                                   w1T, w2T, wcb, wmb, b1f, b2f, ln1wf, ln1bf,
                                   ln2wf, ln2bf, mbf, ln3wf, ln3bf);
    ktrans<<<dim3(8, 128, 4), 256, 0, stream>>>(x, xT, flag);
    k1<<<NPIX, 128, 0, stream>>>(xT, w1T, b1f, w2T, b2f, ln1wf, ln1bf, y1);
    k23<<<NPIX / 32, 256, 0, stream>>>(y1, xT, wcb, wmb, mbf,
                                       ln2wf, ln2bf, ln3wf, ln3bf, d_out, flag);
}

// Round 5
// 409.309 us; speedup vs baseline: 2.4660x; 1.4704x over previous
//
#include <hip/hip_runtime.h>

typedef unsigned short ushort_t;
typedef unsigned int uint_t;

#define NB 4
#define NC 128
#define NH 128
#define NW 128
#define NPIX 65536   // NB*NH*NW
#define NMID 32
#define NKK 49
#define NK 392
#define NKP 400      // NK padded to 25 n-tiles of 16
#define NO 256
#define LN_EPS 1e-6f

typedef __attribute__((ext_vector_type(8))) short short8;
typedef __attribute__((ext_vector_type(4))) float floatx4;

__device__ __forceinline__ float bf2f(ushort_t u) {
    union { uint_t i; float f; } v; v.i = ((uint_t)u) << 16; return v.f;
}
__device__ __forceinline__ ushort_t f2bf(float f) {
    union { float f; uint_t i; } v; v.f = f;
    uint_t x = v.i;
    uint_t r = (x + 0x7FFFu + ((x >> 16) & 1u)) >> 16;
    return (ushort_t)r;
}
__device__ __forceinline__ float gelu_f(float x) {
    return 0.5f * x * (1.0f + erff(x * 0.70710678118654752f));
}
__device__ __forceinline__ float ldin(const void* p, int i, int isf32) {
    return isf32 ? ((const float*)p)[i] : bf2f(((const ushort_t*)p)[i]);
}

// ---------------------------------------------------------------------------
// KD: dtype detector (fp32 vs bf16 input buffers). flag[0]=1 if fp32.
// 64 lanes x 8 words, wave-reduce.
// ---------------------------------------------------------------------------
__global__ void kdetect(const uint_t* __restrict__ xw, int* __restrict__ flag) {
    int lane = threadIdx.x;
    int cnt = 0;
    for (int j = 0; j < 8; j++) {
        uint_t w = xw[lane * 8 + j];
        uint_t e = (w >> 7) & 0xffu;
        if (e >= 110u && e <= 135u) cnt++;
    }
    for (int d = 1; d < 64; d <<= 1) cnt += __shfl_xor(cnt, d);
    if (lane == 0) flag[0] = (cnt < 256) ? 1 : 0;
}

__global__ void ksentinel(uint_t* __restrict__ out, int nwords) {
    int i = blockIdx.x * 256 + threadIdx.x;
    if (i < nwords) out[i] = 0x40004000u;
}

// ---------------------------------------------------------------------------
// K0a: transpose x (B,C,H,W) -> xT (B,H,W,C) canonical bf16.
// ---------------------------------------------------------------------------
__global__ __launch_bounds__(256) void ktrans(const void* __restrict__ x,
                                              ushort_t* __restrict__ xT,
                                              const int* __restrict__ flag) {
    int isf32 = flag[0];
    int b = blockIdx.z, h = blockIdx.y;
    int wchunk = blockIdx.x & 1, cchunk = blockIdx.x >> 1;
    int w0 = wchunk << 6, c0 = cchunk << 5;
    __shared__ ushort_t tile[32][66];
    int tx = threadIdx.x & 63, ty = threadIdx.x >> 6;
    for (int r = 0; r < 32; r += 4) {
        int idx = (((b * NC + c0 + r + ty) * NH) + h) * NW + w0 + tx;
        tile[r + ty][tx] = isf32 ? f2bf(((const float*)x)[idx])
                                 : ((const ushort_t*)x)[idx];
    }
    __syncthreads();
    int cc = threadIdx.x & 31, wq = threadIdx.x >> 5;
    for (int pp = 0; pp < 64; pp += 8) {
        int wx = pp + wq;
        xT[((size_t)((b * NH + h) * NW) + w0 + wx) * NC + c0 + cc] = tile[cc][wx];
    }
}

// ---------------------------------------------------------------------------
// K0b: param prep. w1b/w2b/wcb/wmb bf16 row-major for MFMA B-operands;
// small vectors -> fp32 (b2f zero-padded to 400).
// ---------------------------------------------------------------------------
__global__ __launch_bounds__(256) void kprep(const void* w1, const void* w2,
                                             const void* conv_w, const void* map_w,
                                             const void* b1, const void* b2,
                                             const void* ln1w, const void* ln1b,
                                             const void* ln2w, const void* ln2b,
                                             const void* map_b,
                                             const void* ln3w, const void* ln3b,
                                             const int* __restrict__ flag,
                                             ushort_t* __restrict__ w1b,
                                             ushort_t* __restrict__ w2b,
                                             ushort_t* __restrict__ wcb,
                                             ushort_t* __restrict__ wmb,
                                             float* __restrict__ b1f,
                                             float* __restrict__ b2f,
                                             float* __restrict__ ln1wf,
                                             float* __restrict__ ln1bf,
                                             float* __restrict__ ln2wf,
                                             float* __restrict__ ln2bf,
                                             float* __restrict__ mbf,
                                             float* __restrict__ ln3wf,
                                             float* __restrict__ ln3bf) {
    int isf32 = flag[0];
    int i = blockIdx.x * 256 + threadIdx.x;
    if (i < NMID * NC) w1b[i] = f2bf(ldin(w1, i, isf32));
    if (i < NKP * NMID) w2b[i] = (i < NK * NMID) ? f2bf(ldin(w2, i, isf32))
                                                 : (ushort_t)0;
    wcb[i] = f2bf(ldin(conv_w, i, isf32));
    wmb[i] = f2bf(ldin(map_w, i, isf32));
    if (i < NMID) b1f[i] = ldin(b1, i, isf32);
    if (i < NKP)  b2f[i] = (i < NK) ? ldin(b2, i, isf32) : 0.f;
    if (i < NC) { ln1wf[i] = ldin(ln1w, i, isf32); ln1bf[i] = ldin(ln1b, i, isf32); }
    if (i < NO) {
        ln2wf[i] = ldin(ln2w, i, isf32); ln2bf[i] = ldin(ln2b, i, isf32);
        mbf[i]   = ldin(map_b, i, isf32);
        ln3wf[i] = ldin(ln3w, i, isf32); ln3bf[i] = ldin(ln3b, i, isf32);
    }
}

// ---------------------------------------------------------------------------
// K1: involution + LN(128) + GELU. One WAVE per block; 16 px (2 rows x 8 cols).
// mid = relu(x@w1^T+b1) via MFMA (16x32x128); wk = mid@w2^T+b2 via MFMA
// (16x400x32, zero-padded); wk in wave-private LDS; involution reads xT
// neighbors from global (L1/L2-served); LN via 64-lane butterfly.
// grid (16, 64, 4), block 64.
// ---------------------------------------------------------------------------
__global__ __launch_bounds__(64) void k1(const ushort_t* __restrict__ xT,
                                         const ushort_t* __restrict__ w1b,
                                         const float* __restrict__ b1f,
                                         const ushort_t* __restrict__ w2b,
                                         const float* __restrict__ b2f,
                                         const float* __restrict__ ln1wf,
                                         const float* __restrict__ ln1bf,
                                         ushort_t* __restrict__ y1) {
    __shared__ ushort_t midbuf[16 * 32];    // [px16][m32] bf16
    __shared__ ushort_t wkbuf[16 * NKP];    // [px16][n400] bf16

    int lane = threadIdx.x;
    int l16 = lane & 15, quad = lane >> 4;
    int b = blockIdx.z;
    int h0 = blockIdx.y * 2, w0 = blockIdx.x * 8;

    // ---- mid GEMM: A[m=l16 px][k=quad*8+j] from global xT ----
    int Pa = (b * NH + h0 + (l16 >> 3)) * NW + w0 + (l16 & 7);
    const ushort_t* abase = xT + (size_t)Pa * NC + quad * 8;
    floatx4 am0 = (floatx4)0.f, am1 = (floatx4)0.f;
#pragma unroll
    for (int kb = 0; kb < 4; kb++) {
        short8 a   = *(const short8*)(abase + kb * 32);
        short8 b0  = *(const short8*)(w1b + (l16) * NC + kb * 32 + quad * 8);
        short8 b1v = *(const short8*)(w1b + (16 + l16) * NC + kb * 32 + quad * 8);
        am0 = __builtin_amdgcn_mfma_f32_16x16x32_bf16(a, b0, am0, 0, 0, 0);
        am1 = __builtin_amdgcn_mfma_f32_16x16x32_bf16(a, b1v, am1, 0, 0, 0);
    }
    {
        float bia0 = b1f[l16], bia1 = b1f[16 + l16];
#pragma unroll
        for (int r = 0; r < 4; r++) {
            int m = quad * 4 + r;   // px
            midbuf[m * 32 + l16]      = f2bf(fmaxf(am0[r] + bia0, 0.f));
            midbuf[m * 32 + 16 + l16] = f2bf(fmaxf(am1[r] + bia1, 0.f));
        }
    }
    __syncthreads();   // single wave: just orders LDS write->read

    // ---- wk GEMM: A[m=l16 px][k=quad*8+j] from midbuf; 25 N-tiles ----
    short8 aM = *(const short8*)(midbuf + l16 * 32 + quad * 8);
#pragma unroll
    for (int nt = 0; nt < 25; nt++) {
        int n = nt * 16 + l16;
        short8 bw = *(const short8*)(w2b + n * 32 + quad * 8);
        floatx4 c = __builtin_amdgcn_mfma_f32_16x16x32_bf16(aM, bw, (floatx4)0.f, 0, 0, 0);
        float bias = b2f[n];
#pragma unroll
        for (int r = 0; r < 4; r++)
            wkbuf[(quad * 4 + r) * NKP + n] = f2bf(c[r] + bias);
    }
    __syncthreads();

    // ---- involution + LN + GELU; lane = channel pair ----
    int g = lane >> 3;                       // group of channels 2*lane, 2*lane+1
    float l1w0 = ln1wf[2 * lane], l1w1 = ln1wf[2 * lane + 1];
    float l1b0 = ln1bf[2 * lane], l1b1 = ln1bf[2 * lane + 1];

    for (int i = 0; i < 16; i++) {
        int hh0 = h0 + (i >> 3), ww0 = w0 + (i & 7);
        int p = (b * NH + hh0) * NW + ww0;
        const ushort_t* wkrow = wkbuf + i * NKP + g * NKK;
        float a0 = 0.f, a1 = 0.f;
#pragma unroll
        for (int dy = -3; dy <= 3; dy++) {
            int hh = hh0 + dy;
            if ((unsigned)hh >= (unsigned)NH) continue;   // wave-uniform
#pragma unroll
            for (int dx = -3; dx <= 3; dx++) {
                int ww = ww0 + dx;
                if ((unsigned)ww >= (unsigned)NW) continue;  // wave-uniform
                float wkv = bf2f(wkrow[(dy + 3) * 7 + (dx + 3)]);
                uint_t xp = *(const uint_t*)(xT + ((size_t)(p + dy * NW + dx)) * NC + 2 * lane);
                a0 = fmaf(wkv, bf2f((ushort_t)(xp & 0xffffu)), a0);
                a1 = fmaf(wkv, bf2f((ushort_t)(xp >> 16)), a1);
            }
        }
        float s = a0 + a1, sq = a0 * a0 + a1 * a1;
#pragma unroll
        for (int d = 1; d < 64; d <<= 1) {
            s  += __shfl_xor(s, d);
            sq += __shfl_xor(sq, d);
        }
        float mean = s * (1.0f / NC);
        float var = sq * (1.0f / NC) - mean * mean;
        float rstd = rsqrtf(var + LN_EPS);
        float g0 = gelu_f((a0 - mean) * rstd * l1w0 + l1b0);
        float g1 = gelu_f((a1 - mean) * rstd * l1w1 + l1b1);
        uint_t pk = (uint_t)f2bf(g0) | ((uint_t)f2bf(g1) << 16);
        *(uint_t*)(y1 + (size_t)p * NC + 2 * lane) = pk;
    }
}

// ---------------------------------------------------------------------------
// K23 (MFMA): conv(y1)+LN2, map(x)+LN3, add, GELU -> out.
// Block = 256 thr = 4 waves; 32 pixels x 256 outputs x both branches.
// LDS cut to 19.5 KB (two-pass epilogue through 128x33 f32 obuf) -> 8 blk/CU.
// grid 2048.
// ---------------------------------------------------------------------------
__global__ __launch_bounds__(256) void k23(const ushort_t* __restrict__ y1,
                                           const ushort_t* __restrict__ xT,
                                           const ushort_t* __restrict__ wcb,
                                           const ushort_t* __restrict__ wmb,
                                           const float* __restrict__ mbf,
                                           const float* __restrict__ ln2wf,
                                           const float* __restrict__ ln2bf,
                                           const float* __restrict__ ln3wf,
                                           const float* __restrict__ ln3bf,
                                           void* __restrict__ out,
                                           const int* __restrict__ flag) {
    // [0,8K) ybufF | [8K,16K) xbufF  -- overlaid by obuf [0,16896)
    // sred at 16896 (2048 B) | sstat at 18944 (512 B)
    __shared__ __align__(16) char smem[19456];
    ushort_t* ybufF = (ushort_t*)smem;
    ushort_t* xbufF = (ushort_t*)(smem + 8192);
    float*    obuf  = (float*)smem;                  // [128][33] per pass
    float*    sred  = (float*)(smem + 16896);        // [4][32][4]
    float*    sstat = (float*)(smem + 18944);        // [32][4]

    int isf32 = flag[0];
    int t = threadIdx.x;
    int P0 = blockIdx.x * 32;

    // --- stage A tiles (y and x) into fragment-ordered LDS -----------------
    for (int rep = 0; rep < 2; rep++) {
        int q = rep * 256 + t;
        int pl = q & 15, quad_ = (q >> 4) & 3, kb = (q >> 6) & 3, mt = (q >> 8) & 1;
        int p = mt * 16 + pl;
        int c0 = kb * 32 + quad_ * 8;
        size_t src = (size_t)(P0 + p) * NC + c0;
        int dst = ((mt * 4 + kb) * 64 + quad_ * 16 + pl) * 8;
        *(uint4*)&ybufF[dst] = *(const uint4*)&y1[src];
        *(uint4*)&xbufF[dst] = *(const uint4*)&xT[src];
    }
    __syncthreads();

    int lane = t & 63;
    int w = __builtin_amdgcn_readfirstlane(t >> 6);  // wave id 0..3
    int quad = lane >> 4;
    int l16 = lane & 15;

    floatx4 accC[2][4], accM[2][4];
#pragma unroll
    for (int mt = 0; mt < 2; mt++)
#pragma unroll
        for (int nt = 0; nt < 4; nt++) {
            accC[mt][nt] = (floatx4)0.0f;
            accM[mt][nt] = (floatx4)0.0f;
        }

#pragma unroll
    for (int kb = 0; kb < 4; kb++) {
        short8 aY0 = *(const short8*)&ybufF[((0 * 4 + kb) * 64 + lane) * 8];
        short8 aY1 = *(const short8*)&ybufF[((1 * 4 + kb) * 64 + lane) * 8];
        short8 aX0 = *(const short8*)&xbufF[((0 * 4 + kb) * 64 + lane) * 8];
        short8 aX1 = *(const short8*)&xbufF[((1 * 4 + kb) * 64 + lane) * 8];
#pragma unroll
        for (int nt = 0; nt < 4; nt++) {
            int o = w * 64 + nt * 16 + l16;
            size_t boff = (size_t)o * NC + kb * 32 + quad * 8;
            short8 bc = *(const short8*)&wcb[boff];
            short8 bm = *(const short8*)&wmb[boff];
            accC[0][nt] = __builtin_amdgcn_mfma_f32_16x16x32_bf16(aY0, bc, accC[0][nt], 0, 0, 0);
            accC[1][nt] = __builtin_amdgcn_mfma_f32_16x16x32_bf16(aY1, bc, accC[1][nt], 0, 0, 0);
            accM[0][nt] = __builtin_amdgcn_mfma_f32_16x16x32_bf16(aX0, bm, accM[0][nt], 0, 0, 0);
            accM[1][nt] = __builtin_amdgcn_mfma_f32_16x16x32_bf16(aX1, bm, accM[1][nt], 0, 0, 0);
        }
    }

    float mb_[4], l2w_[4], l2b_[4], l3w_[4], l3b_[4];
#pragma unroll
    for (int nt = 0; nt < 4; nt++) {
        int o = w * 64 + nt * 16 + l16;
        mb_[nt] = mbf[o];
        l2w_[nt] = ln2wf[o]; l2b_[nt] = ln2bf[o];
        l3w_[nt] = ln3wf[o]; l3b_[nt] = ln3bf[o];
    }
#pragma unroll
    for (int mt = 0; mt < 2; mt++)
#pragma unroll
        for (int nt = 0; nt < 4; nt++)
#pragma unroll
            for (int r = 0; r < 4; r++)
                accM[mt][nt][r] += mb_[nt];

#pragma unroll
    for (int mt = 0; mt < 2; mt++) {
#pragma unroll
        for (int r = 0; r < 4; r++) {
            float s1 = 0.f, s1q = 0.f, s2 = 0.f, s2q = 0.f;
#pragma unroll
            for (int nt = 0; nt < 4; nt++) {
                float a = accC[mt][nt][r], m = accM[mt][nt][r];
                s1 += a; s1q += a * a; s2 += m; s2q += m * m;
            }
#pragma unroll
            for (int d = 1; d < 16; d <<= 1) {
                s1  += __shfl_xor(s1, d);
                s1q += __shfl_xor(s1q, d);
                s2  += __shfl_xor(s2, d);
                s2q += __shfl_xor(s2q, d);
            }
            if (l16 == 0) {
                int px = mt * 16 + quad * 4 + r;
                float* sp = sred + ((w * 32 + px) * 4);
                sp[0] = s1; sp[1] = s1q; sp[2] = s2; sp[3] = s2q;
            }
        }
    }
    __syncthreads();   // A-tile reads also complete here

    if (t < 32) {
        float a0 = 0.f, a1 = 0.f, a2 = 0.f, a3 = 0.f;
        for (int ww = 0; ww < 4; ww++) {
            const float* sp = sred + ((ww * 32 + t) * 4);
            a0 += sp[0]; a1 += sp[1]; a2 += sp[2]; a3 += sp[3];
        }
        float m1 = a0 * (1.0f / NO);
        float v1 = a1 * (1.0f / NO) - m1 * m1;
        float m2 = a2 * (1.0f / NO);
        float v2 = a3 * (1.0f / NO) - m2 * m2;
        float* st = sstat + t * 4;
        st[0] = m1; st[1] = rsqrtf(v1 + LN_EPS);
        st[2] = m2; st[3] = rsqrtf(v2 + LN_EPS);
    }
    __syncthreads();

    // --- two-pass epilogue: normalize+gelu -> obuf -> coalesced store ------
    int batch = P0 >> 14;
    int plocal0 = P0 & 16383;
#pragma unroll
    for (int pass = 0; pass < 2; pass++) {
#pragma unroll
        for (int ntl = 0; ntl < 2; ntl++) {
            int nt = 2 * pass + ntl;
#pragma unroll
            for (int mt = 0; mt < 2; mt++) {
#pragma unroll
                for (int r = 0; r < 4; r++) {
                    int px = mt * 16 + quad * 4 + r;
                    const float* st = sstat + px * 4;
                    float v1 = (accC[mt][nt][r] - st[0]) * st[1] * l2w_[nt] + l2b_[nt];
                    float v2 = (accM[mt][nt][r] - st[2]) * st[3] * l3w_[nt] + l3b_[nt];
                    obuf[(w * 32 + ntl * 16 + l16) * 33 + px] = gelu_f(v1 + v2);
                }
            }
        }
        __syncthreads();
        for (int it = 0; it < 16; it++) {
            int idx = it * 256 + t;
            int lr = idx >> 5, px = idx & 31;
            int o = (lr >> 5) * 64 + 32 * pass + (lr & 31);
            float val = obuf[lr * 33 + px];
            size_t oi = ((size_t)(batch * NO + o) << 14) + plocal0 + px;
            if (isf32) ((float*)out)[oi] = val;
            else       ((ushort_t*)out)[oi] = f2bf(val);
        }
        __syncthreads();
    }
}

// ---------------------------------------------------------------------------
extern "C" void kernel_launch(void* const* d_in, const int* in_sizes, int n_in,
                              void* d_out, int out_size, void* d_ws, size_t ws_size,
                              hipStream_t stream) {
    const void* x      = d_in[0];
    const void* w1     = d_in[1];
    const void* b1     = d_in[2];
    const void* w2     = d_in[3];
    const void* b2     = d_in[4];
    const void* ln1w   = d_in[5];
    const void* ln1b   = d_in[6];
    const void* conv_w = d_in[7];
    const void* ln2w   = d_in[8];
    const void* ln2b   = d_in[9];
    const void* map_w  = d_in[10];
    const void* map_b  = d_in[11];
    const void* ln3w   = d_in[12];
    const void* ln3b   = d_in[13];

    char* ws = (char*)d_ws;
    ushort_t* xT    = (ushort_t*)(ws);                  // 16,777,216 B
    ushort_t* y1    = (ushort_t*)(ws + 16777216);       // 16,777,216 B
    ushort_t* wcb   = (ushort_t*)(ws + 33554432);       //  65,536 B
    ushort_t* wmb   = (ushort_t*)(ws + 33619968);       //  65,536 B
    ushort_t* w1b   = (ushort_t*)(ws + 33685504);       //   8,192 B
    ushort_t* w2b   = (ushort_t*)(ws + 33693696);       //  25,600 B
    float*    b1f   = (float*)(ws + 33719296);          //     128 B
    float*    b2f   = (float*)(ws + 33719424);          //   1,600 B
    float*    ln1wf = (float*)(ws + 33721024);          //     512 B
    float*    ln1bf = (float*)(ws + 33721536);          //     512 B
    float*    mbf   = (float*)(ws + 33722048);          //   1,024 B
    float*    ln2wf = (float*)(ws + 33723072);          //   1,024 B
    float*    ln2bf = (float*)(ws + 33724096);          //   1,024 B
    float*    ln3wf = (float*)(ws + 33725120);          //   1,024 B
    float*    ln3bf = (float*)(ws + 33726144);          //   1,024 B
    int*      flag  = (int*)(ws + 33727168);            //      16 B
    const size_t NEED = 33727184;

    if (ws_size < NEED) {
        int nwords = out_size / 2;
        ksentinel<<<(nwords + 255) / 256, 256, 0, stream>>>((uint_t*)d_out, nwords);
        return;
    }

    kdetect<<<1, 64, 0, stream>>>((const uint_t*)x, flag);
    kprep<<<128, 256, 0, stream>>>(w1, w2, conv_w, map_w, b1, b2, ln1w, ln1b,
                                   ln2w, ln2b, map_b, ln3w, ln3b, flag,
                                   w1b, w2b, wcb, wmb, b1f, b2f, ln1wf, ln1bf,
                                   ln2wf, ln2bf, mbf, ln3wf, ln3bf);
    ktrans<<<dim3(8, 128, 4), 256, 0, stream>>>(x, xT, flag);
    k1<<<dim3(16, 64, 4), 64, 0, stream>>>(xT, w1b, b1f, w2b, b2f, ln1wf, ln1bf, y1);
    k23<<<NPIX / 32, 256, 0, stream>>>(y1, xT, wcb, wmb, mbf,
                                       ln2wf, ln2bf, ln3wf, ln3bf, d_out, flag);
}

// Round 6
// 344.115 us; speedup vs baseline: 2.9331x; 1.1895x over previous
//
#include <hip/hip_runtime.h>

typedef unsigned short ushort_t;
typedef unsigned int uint_t;

#define NB 4
#define NC 128
#define NH 128
#define NW 128
#define NPIX 65536   // NB*NH*NW
#define NMID 32
#define NKK 49
#define NK 392
#define NKP 400      // NK padded to 25 n-tiles of 16
#define NO 256
#define LN_EPS 1e-6f

typedef __attribute__((ext_vector_type(8))) short short8;
typedef __attribute__((ext_vector_type(4))) float floatx4;

__device__ __forceinline__ float bf2f(ushort_t u) {
    union { uint_t i; float f; } v; v.i = ((uint_t)u) << 16; return v.f;
}
__device__ __forceinline__ ushort_t f2bf(float f) {
    union { float f; uint_t i; } v; v.f = f;
    uint_t x = v.i;
    uint_t r = (x + 0x7FFFu + ((x >> 16) & 1u)) >> 16;
    return (ushort_t)r;
}
__device__ __forceinline__ float gelu_f(float x) {
    return 0.5f * x * (1.0f + erff(x * 0.70710678118654752f));
}
__device__ __forceinline__ float ldin(const void* p, int i, int isf32) {
    return isf32 ? ((const float*)p)[i] : bf2f(((const ushort_t*)p)[i]);
}

// ---------------------------------------------------------------------------
__global__ void kdetect(const uint_t* __restrict__ xw, int* __restrict__ flag) {
    int lane = threadIdx.x;
    int cnt = 0;
    for (int j = 0; j < 8; j++) {
        uint_t w = xw[lane * 8 + j];
        uint_t e = (w >> 7) & 0xffu;
        if (e >= 110u && e <= 135u) cnt++;
    }
    for (int d = 1; d < 64; d <<= 1) cnt += __shfl_xor(cnt, d);
    if (lane == 0) flag[0] = (cnt < 256) ? 1 : 0;
}

__global__ void ksentinel(uint_t* __restrict__ out, int nwords) {
    int i = blockIdx.x * 256 + threadIdx.x;
    if (i < nwords) out[i] = 0x40004000u;
}

// ---------------------------------------------------------------------------
// K0a: transpose x (B,C,H,W) -> xT (B,H,W,C) canonical bf16.
// ---------------------------------------------------------------------------
__global__ __launch_bounds__(256) void ktrans(const void* __restrict__ x,
                                              ushort_t* __restrict__ xT,
                                              const int* __restrict__ flag) {
    int isf32 = flag[0];
    int b = blockIdx.z, h = blockIdx.y;
    int wchunk = blockIdx.x & 1, cchunk = blockIdx.x >> 1;
    int w0 = wchunk << 6, c0 = cchunk << 5;
    __shared__ ushort_t tile[32][66];
    int tx = threadIdx.x & 63, ty = threadIdx.x >> 6;
    for (int r = 0; r < 32; r += 4) {
        int idx = (((b * NC + c0 + r + ty) * NH) + h) * NW + w0 + tx;
        tile[r + ty][tx] = isf32 ? f2bf(((const float*)x)[idx])
                                 : ((const ushort_t*)x)[idx];
    }
    __syncthreads();
    int cc = threadIdx.x & 31, wq = threadIdx.x >> 5;
    for (int pp = 0; pp < 64; pp += 8) {
        int wx = pp + wq;
        xT[((size_t)((b * NH + h) * NW) + w0 + wx) * NC + c0 + cc] = tile[cc][wx];
    }
}

// ---------------------------------------------------------------------------
// K0b: param prep.
// ---------------------------------------------------------------------------
__global__ __launch_bounds__(256) void kprep(const void* w1, const void* w2,
                                             const void* conv_w, const void* map_w,
                                             const void* b1, const void* b2,
                                             const void* ln1w, const void* ln1b,
                                             const void* ln2w, const void* ln2b,
                                             const void* map_b,
                                             const void* ln3w, const void* ln3b,
                                             const int* __restrict__ flag,
                                             ushort_t* __restrict__ w1b,
                                             ushort_t* __restrict__ w2b,
                                             ushort_t* __restrict__ wcb,
                                             ushort_t* __restrict__ wmb,
                                             float* __restrict__ b1f,
                                             float* __restrict__ b2f,
                                             float* __restrict__ ln1wf,
                                             float* __restrict__ ln1bf,
                                             float* __restrict__ ln2wf,
                                             float* __restrict__ ln2bf,
                                             float* __restrict__ mbf,
                                             float* __restrict__ ln3wf,
                                             float* __restrict__ ln3bf) {
    int isf32 = flag[0];
    int i = blockIdx.x * 256 + threadIdx.x;
    if (i < NMID * NC) w1b[i] = f2bf(ldin(w1, i, isf32));
    if (i < NKP * NMID) w2b[i] = (i < NK * NMID) ? f2bf(ldin(w2, i, isf32))
                                                 : (ushort_t)0;
    wcb[i] = f2bf(ldin(conv_w, i, isf32));
    wmb[i] = f2bf(ldin(map_w, i, isf32));
    if (i < NMID) b1f[i] = ldin(b1, i, isf32);
    if (i < NKP)  b2f[i] = (i < NK) ? ldin(b2, i, isf32) : 0.f;
    if (i < NC) { ln1wf[i] = ldin(ln1w, i, isf32); ln1bf[i] = ldin(ln1b, i, isf32); }
    if (i < NO) {
        ln2wf[i] = ldin(ln2w, i, isf32); ln2bf[i] = ldin(ln2b, i, isf32);
        mbf[i]   = ldin(map_b, i, isf32);
        ln3wf[i] = ldin(ln3w, i, isf32); ln3bf[i] = ldin(ln3b, i, isf32);
    }
}

// ---------------------------------------------------------------------------
// K1a: wk producer. Block = 256 thr (4 waves), tile = 64 px (8x8).
// Wave w: tile-local px [16w,16w+16). mid GEMM (8 MFMA) -> wk GEMM (25 MFMA)
// -> wkstage LDS -> coalesced wkT[k][tile*64+lpx] stores.
// grid 1024 = (tilex 16) x (tiley 16) x (b 4).
// ---------------------------------------------------------------------------
__global__ __launch_bounds__(256) void k1a(const ushort_t* __restrict__ xT,
                                           const ushort_t* __restrict__ w1b,
                                           const float* __restrict__ b1f,
                                           const ushort_t* __restrict__ w2b,
                                           const float* __restrict__ b2f,
                                           ushort_t* __restrict__ wkT) {
    __shared__ ushort_t midbuf[64 * 32];        // [lpx][m]
    __shared__ ushort_t wkstage[NKP * 66];      // [k][lpx] padded 64->66

    int t = threadIdx.x;
    int lane = t & 63;
    int w = __builtin_amdgcn_readfirstlane(t >> 6);
    int l16 = lane & 15, quad = lane >> 4;
    int tileid = blockIdx.x;
    int tilex = tileid & 15, tiley = (tileid >> 4) & 15, b = tileid >> 8;
    int h0 = tiley * 8, w0 = tilex * 8;

    // ---- mid GEMM ----
    int lpx_a = 16 * w + l16;
    int py = lpx_a >> 3, pxx = lpx_a & 7;
    const ushort_t* abase = xT + (size_t)((b * NH + h0 + py) * NW + w0 + pxx) * NC + quad * 8;
    floatx4 am0 = (floatx4)0.f, am1 = (floatx4)0.f;
#pragma unroll
    for (int kb = 0; kb < 4; kb++) {
        short8 a   = *(const short8*)(abase + kb * 32);
        short8 b0  = *(const short8*)(w1b + (l16) * NC + kb * 32 + quad * 8);
        short8 b1v = *(const short8*)(w1b + (16 + l16) * NC + kb * 32 + quad * 8);
        am0 = __builtin_amdgcn_mfma_f32_16x16x32_bf16(a, b0, am0, 0, 0, 0);
        am1 = __builtin_amdgcn_mfma_f32_16x16x32_bf16(a, b1v, am1, 0, 0, 0);
    }
    {
        float bia0 = b1f[l16], bia1 = b1f[16 + l16];
#pragma unroll
        for (int r = 0; r < 4; r++) {
            int m = 16 * w + quad * 4 + r;   // tile-local px
            midbuf[m * 32 + l16]      = f2bf(fmaxf(am0[r] + bia0, 0.f));
            midbuf[m * 32 + 16 + l16] = f2bf(fmaxf(am1[r] + bia1, 0.f));
        }
    }
    __syncthreads();

    // ---- wk GEMM ----
    short8 aM = *(const short8*)(midbuf + (16 * w + l16) * 32 + quad * 8);
#pragma unroll
    for (int nt = 0; nt < 25; nt++) {
        int n = nt * 16 + l16;
        short8 bw = *(const short8*)(w2b + n * 32 + quad * 8);
        floatx4 c = __builtin_amdgcn_mfma_f32_16x16x32_bf16(aM, bw, (floatx4)0.f, 0, 0, 0);
        float bias = b2f[n];
#pragma unroll
        for (int r = 0; r < 4; r++)
            wkstage[n * 66 + 16 * w + quad * 4 + r] = f2bf(c[r] + bias);
    }
    __syncthreads();

    // ---- coalesced stores: 8 k-rows per iteration ----
    int krow = t >> 5, px2 = t & 31;
    for (int it = 0; it < 50; it++) {
        int k = it * 8 + krow;
        uint_t v = *(const uint_t*)&wkstage[k * 66 + 2 * px2];
        *(uint_t*)&wkT[(size_t)k * NPIX + tileid * 64 + 2 * px2] = v;
    }
}

// ---------------------------------------------------------------------------
// K1b: involution + LN + GELU, lane = pixel. Block = 256 thr (4 waves),
// tile 8x8 px + 14x14 halo staged as dwords x2[cpair][197]. Wave w handles
// channels [32w, 32w+32). wk read coalesced from wkT. grid 1024.
// ---------------------------------------------------------------------------
__global__ __launch_bounds__(256) void k1b(const ushort_t* __restrict__ xT,
                                           const ushort_t* __restrict__ wkT,
                                           const float* __restrict__ ln1wf,
                                           const float* __restrict__ ln1bf,
                                           ushort_t* __restrict__ y1) {
    __shared__ uint_t x2[64 * 197];          // [cpair][halo px], 50,432 B
    __shared__ float sred[4][64][2];         // 2,048 B

    int t = threadIdx.x;
    int lane = t & 63;
    int w = __builtin_amdgcn_readfirstlane(t >> 6);
    int tileid = blockIdx.x;
    int tilex = tileid & 15, tiley = (tileid >> 4) & 15, b = tileid >> 8;
    int h0 = tiley * 8, w0 = tilex * 8;

    // ---- stage halo: 196 px x 64 cpairs; 4 px per iteration (wave = px) ----
    for (int it = 0; it < 49; it++) {
        int hp = it * 4 + w;
        int hy = hp / 14, hx = hp % 14;
        int gh = h0 + hy - 3, gw = w0 + hx - 3;
        uint_t v = 0;
        if ((unsigned)gh < (unsigned)NH && (unsigned)gw < (unsigned)NW) {
            v = *(const uint_t*)&xT[(size_t)((b * NH + gh) * NW + gw) * NC + 2 * lane];
        }
        x2[lane * 197 + hp] = v;
    }
    __syncthreads();

    int base0 = (lane >> 3) * 14 + (lane & 7);   // halo addr of own px (+3,+3 origin)
    float a[32];
#pragma unroll
    for (int j = 0; j < 32; j++) a[j] = 0.f;

#pragma unroll
    for (int ghalf = 0; ghalf < 2; ghalf++) {
        int g = 2 * w + ghalf;
        const ushort_t* wkbase = wkT + (size_t)(g * NKK) * NPIX + tileid * 64 + lane;
        float wkv[NKK];
#pragma unroll
        for (int tap = 0; tap < NKK; tap++)
            wkv[tap] = bf2f(wkbase[(size_t)tap * NPIX]);
#pragma unroll
        for (int tap = 0; tap < NKK; tap++) {
            int off = (tap / 7) * 14 + (tap % 7);
            int xa = base0 + off;
#pragma unroll
            for (int j = 0; j < 8; j++) {
                uint_t u = x2[(w * 16 + ghalf * 8 + j) * 197 + xa];
                float lo = bf2f((ushort_t)(u & 0xffffu));
                float hi = bf2f((ushort_t)(u >> 16));
                a[(ghalf * 8 + j) * 2]     = fmaf(wkv[tap], lo, a[(ghalf * 8 + j) * 2]);
                a[(ghalf * 8 + j) * 2 + 1] = fmaf(wkv[tap], hi, a[(ghalf * 8 + j) * 2 + 1]);
            }
        }
    }

    // ---- LN over 128 channels: per-px cross-wave reduce ----
    float s = 0.f, sq = 0.f;
#pragma unroll
    for (int j = 0; j < 32; j++) { s += a[j]; sq += a[j] * a[j]; }
    sred[w][lane][0] = s; sred[w][lane][1] = sq;
    __syncthreads();
    float ts = 0.f, tq = 0.f;
#pragma unroll
    for (int r = 0; r < 4; r++) { ts += sred[r][lane][0]; tq += sred[r][lane][1]; }
    float mean = ts * (1.0f / NC);
    float var = tq * (1.0f / NC) - mean * mean;
    float rstd = rsqrtf(var + LN_EPS);

    int py = lane >> 3, pxx = lane & 7;
    size_t pglob = (size_t)((b * NH + h0 + py) * NW + w0 + pxx);
    uint_t* yrow = (uint_t*)(y1 + pglob * NC);
#pragma unroll
    for (int j = 0; j < 16; j++) {
        int c0 = 2 * (w * 16 + j);
        float g0 = gelu_f((a[2 * j] - mean) * rstd * ln1wf[c0] + ln1bf[c0]);
        float g1 = gelu_f((a[2 * j + 1] - mean) * rstd * ln1wf[c0 + 1] + ln1bf[c0 + 1]);
        yrow[w * 16 + j] = (uint_t)f2bf(g0) | ((uint_t)f2bf(g1) << 16);
    }
}

// ---------------------------------------------------------------------------
// K1 fused fallback (round-5 version) — used only if ws too small for wkT.
// ---------------------------------------------------------------------------
__global__ __launch_bounds__(64) void k1_fused(const ushort_t* __restrict__ xT,
                                               const ushort_t* __restrict__ w1b,
                                               const float* __restrict__ b1f,
                                               const ushort_t* __restrict__ w2b,
                                               const float* __restrict__ b2f,
                                               const float* __restrict__ ln1wf,
                                               const float* __restrict__ ln1bf,
                                               ushort_t* __restrict__ y1) {
    __shared__ ushort_t midbuf[16 * 32];
    __shared__ ushort_t wkbuf[16 * NKP];

    int lane = threadIdx.x;
    int l16 = lane & 15, quad = lane >> 4;
    int b = blockIdx.z;
    int h0 = blockIdx.y * 2, w0 = blockIdx.x * 8;

    int Pa = (b * NH + h0 + (l16 >> 3)) * NW + w0 + (l16 & 7);
    const ushort_t* abase = xT + (size_t)Pa * NC + quad * 8;
    floatx4 am0 = (floatx4)0.f, am1 = (floatx4)0.f;
#pragma unroll
    for (int kb = 0; kb < 4; kb++) {
        short8 a   = *(const short8*)(abase + kb * 32);
        short8 b0  = *(const short8*)(w1b + (l16) * NC + kb * 32 + quad * 8);
        short8 b1v = *(const short8*)(w1b + (16 + l16) * NC + kb * 32 + quad * 8);
        am0 = __builtin_amdgcn_mfma_f32_16x16x32_bf16(a, b0, am0, 0, 0, 0);
        am1 = __builtin_amdgcn_mfma_f32_16x16x32_bf16(a, b1v, am1, 0, 0, 0);
    }
    {
        float bia0 = b1f[l16], bia1 = b1f[16 + l16];
#pragma unroll
        for (int r = 0; r < 4; r++) {
            int m = quad * 4 + r;
            midbuf[m * 32 + l16]      = f2bf(fmaxf(am0[r] + bia0, 0.f));
            midbuf[m * 32 + 16 + l16] = f2bf(fmaxf(am1[r] + bia1, 0.f));
        }
    }
    __syncthreads();

    short8 aM = *(const short8*)(midbuf + l16 * 32 + quad * 8);
#pragma unroll
    for (int nt = 0; nt < 25; nt++) {
        int n = nt * 16 + l16;
        short8 bw = *(const short8*)(w2b + n * 32 + quad * 8);
        floatx4 c = __builtin_amdgcn_mfma_f32_16x16x32_bf16(aM, bw, (floatx4)0.f, 0, 0, 0);
        float bias = b2f[n];
#pragma unroll
        for (int r = 0; r < 4; r++)
            wkbuf[(quad * 4 + r) * NKP + n] = f2bf(c[r] + bias);
    }
    __syncthreads();

    int g = lane >> 3;
    float l1w0 = ln1wf[2 * lane], l1w1 = ln1wf[2 * lane + 1];
    float l1b0 = ln1bf[2 * lane], l1b1 = ln1bf[2 * lane + 1];

    for (int i = 0; i < 16; i++) {
        int hh0 = h0 + (i >> 3), ww0 = w0 + (i & 7);
        int p = (b * NH + hh0) * NW + ww0;
        const ushort_t* wkrow = wkbuf + i * NKP + g * NKK;
        float a0 = 0.f, a1 = 0.f;
#pragma unroll
        for (int dy = -3; dy <= 3; dy++) {
            int hh = hh0 + dy;
            if ((unsigned)hh >= (unsigned)NH) continue;
#pragma unroll
            for (int dx = -3; dx <= 3; dx++) {
                int ww = ww0 + dx;
                if ((unsigned)ww >= (unsigned)NW) continue;
                float wkv = bf2f(wkrow[(dy + 3) * 7 + (dx + 3)]);
                uint_t xp = *(const uint_t*)(xT + ((size_t)(p + dy * NW + dx)) * NC + 2 * lane);
                a0 = fmaf(wkv, bf2f((ushort_t)(xp & 0xffffu)), a0);
                a1 = fmaf(wkv, bf2f((ushort_t)(xp >> 16)), a1);
            }
        }
        float s = a0 + a1, sq = a0 * a0 + a1 * a1;
#pragma unroll
        for (int d = 1; d < 64; d <<= 1) {
            s  += __shfl_xor(s, d);
            sq += __shfl_xor(sq, d);
        }
        float mean = s * (1.0f / NC);
        float var = sq * (1.0f / NC) - mean * mean;
        float rstd = rsqrtf(var + LN_EPS);
        float g0 = gelu_f((a0 - mean) * rstd * l1w0 + l1b0);
        float g1 = gelu_f((a1 - mean) * rstd * l1w1 + l1b1);
        uint_t pk = (uint_t)f2bf(g0) | ((uint_t)f2bf(g1) << 16);
        *(uint_t*)(y1 + (size_t)p * NC + 2 * lane) = pk;
    }
}

// ---------------------------------------------------------------------------
// K23 (unchanged from round 5).
// ---------------------------------------------------------------------------
__global__ __launch_bounds__(256) void k23(const ushort_t* __restrict__ y1,
                                           const ushort_t* __restrict__ xT,
                                           const ushort_t* __restrict__ wcb,
                                           const ushort_t* __restrict__ wmb,
                                           const float* __restrict__ mbf,
                                           const float* __restrict__ ln2wf,
                                           const float* __restrict__ ln2bf,
                                           const float* __restrict__ ln3wf,
                                           const float* __restrict__ ln3bf,
                                           void* __restrict__ out,
                                           const int* __restrict__ flag) {
    __shared__ __align__(16) char smem[19456];
    ushort_t* ybufF = (ushort_t*)smem;
    ushort_t* xbufF = (ushort_t*)(smem + 8192);
    float*    obuf  = (float*)smem;
    float*    sred  = (float*)(smem + 16896);
    float*    sstat = (float*)(smem + 18944);

    int isf32 = flag[0];
    int t = threadIdx.x;
    int P0 = blockIdx.x * 32;

    for (int rep = 0; rep < 2; rep++) {
        int q = rep * 256 + t;
        int pl = q & 15, quad_ = (q >> 4) & 3, kb = (q >> 6) & 3, mt = (q >> 8) & 1;
        int p = mt * 16 + pl;
        int c0 = kb * 32 + quad_ * 8;
        size_t src = (size_t)(P0 + p) * NC + c0;
        int dst = ((mt * 4 + kb) * 64 + quad_ * 16 + pl) * 8;
        *(uint4*)&ybufF[dst] = *(const uint4*)&y1[src];
        *(uint4*)&xbufF[dst] = *(const uint4*)&xT[src];
    }
    __syncthreads();

    int lane = t & 63;
    int w = __builtin_amdgcn_readfirstlane(t >> 6);
    int quad = lane >> 4;
    int l16 = lane & 15;

    floatx4 accC[2][4], accM[2][4];
#pragma unroll
    for (int mt = 0; mt < 2; mt++)
#pragma unroll
        for (int nt = 0; nt < 4; nt++) {
            accC[mt][nt] = (floatx4)0.0f;
            accM[mt][nt] = (floatx4)0.0f;
        }

#pragma unroll
    for (int kb = 0; kb < 4; kb++) {
        short8 aY0 = *(const short8*)&ybufF[((0 * 4 + kb) * 64 + lane) * 8];
        short8 aY1 = *(const short8*)&ybufF[((1 * 4 + kb) * 64 + lane) * 8];
        short8 aX0 = *(const short8*)&xbufF[((0 * 4 + kb) * 64 + lane) * 8];
        short8 aX1 = *(const short8*)&xbufF[((1 * 4 + kb) * 64 + lane) * 8];
#pragma unroll
        for (int nt = 0; nt < 4; nt++) {
            int o = w * 64 + nt * 16 + l16;
            size_t boff = (size_t)o * NC + kb * 32 + quad * 8;
            short8 bc = *(const short8*)&wcb[boff];
            short8 bm = *(const short8*)&wmb[boff];
            accC[0][nt] = __builtin_amdgcn_mfma_f32_16x16x32_bf16(aY0, bc, accC[0][nt], 0, 0, 0);
            accC[1][nt] = __builtin_amdgcn_mfma_f32_16x16x32_bf16(aY1, bc, accC[1][nt], 0, 0, 0);
            accM[0][nt] = __builtin_amdgcn_mfma_f32_16x16x32_bf16(aX0, bm, accM[0][nt], 0, 0, 0);
            accM[1][nt] = __builtin_amdgcn_mfma_f32_16x16x32_bf16(aX1, bm, accM[1][nt], 0, 0, 0);
        }
    }

    float mb_[4], l2w_[4], l2b_[4], l3w_[4], l3b_[4];
#pragma unroll
    for (int nt = 0; nt < 4; nt++) {
        int o = w * 64 + nt * 16 + l16;
        mb_[nt] = mbf[o];
        l2w_[nt] = ln2wf[o]; l2b_[nt] = ln2bf[o];
        l3w_[nt] = ln3wf[o]; l3b_[nt] = ln3bf[o];
    }
#pragma unroll
    for (int mt = 0; mt < 2; mt++)
#pragma unroll
        for (int nt = 0; nt < 4; nt++)
#pragma unroll
            for (int r = 0; r < 4; r++)
                accM[mt][nt][r] += mb_[nt];

#pragma unroll
    for (int mt = 0; mt < 2; mt++) {
#pragma unroll
        for (int r = 0; r < 4; r++) {
            float s1 = 0.f, s1q = 0.f, s2 = 0.f, s2q = 0.f;
#pragma unroll
            for (int nt = 0; nt < 4; nt++) {
                float a = accC[mt][nt][r], m = accM[mt][nt][r];
                s1 += a; s1q += a * a; s2 += m; s2q += m * m;
            }
#pragma unroll
            for (int d = 1; d < 16; d <<= 1) {
                s1  += __shfl_xor(s1, d);
                s1q += __shfl_xor(s1q, d);
                s2  += __shfl_xor(s2, d);
                s2q += __shfl_xor(s2q, d);
            }
            if (l16 == 0) {
                int px = mt * 16 + quad * 4 + r;
                float* sp = sred + ((w * 32 + px) * 4);
                sp[0] = s1; sp[1] = s1q; sp[2] = s2; sp[3] = s2q;
            }
        }
    }
    __syncthreads();

    if (t < 32) {
        float a0 = 0.f, a1 = 0.f, a2 = 0.f, a3 = 0.f;
        for (int ww = 0; ww < 4; ww++) {
            const float* sp = sred + ((ww * 32 + t) * 4);
            a0 += sp[0]; a1 += sp[1]; a2 += sp[2]; a3 += sp[3];
        }
        float m1 = a0 * (1.0f / NO);
        float v1 = a1 * (1.0f / NO) - m1 * m1;
        float m2 = a2 * (1.0f / NO);
        float v2 = a3 * (1.0f / NO) - m2 * m2;
        float* st = sstat + t * 4;
        st[0] = m1; st[1] = rsqrtf(v1 + LN_EPS);
        st[2] = m2; st[3] = rsqrtf(v2 + LN_EPS);
    }
    __syncthreads();

    int batch = P0 >> 14;
    int plocal0 = P0 & 16383;
#pragma unroll
    for (int pass = 0; pass < 2; pass++) {
#pragma unroll
        for (int ntl = 0; ntl < 2; ntl++) {
            int nt = 2 * pass + ntl;
#pragma unroll
            for (int mt = 0; mt < 2; mt++) {
#pragma unroll
                for (int r = 0; r < 4; r++) {
                    int px = mt * 16 + quad * 4 + r;
                    const float* st = sstat + px * 4;
                    float v1 = (accC[mt][nt][r] - st[0]) * st[1] * l2w_[nt] + l2b_[nt];
                    float v2 = (accM[mt][nt][r] - st[2]) * st[3] * l3w_[nt] + l3b_[nt];
                    obuf[(w * 32 + ntl * 16 + l16) * 33 + px] = gelu_f(v1 + v2);
                }
            }
        }
        __syncthreads();
        for (int it = 0; it < 16; it++) {
            int idx = it * 256 + t;
            int lr = idx >> 5, px = idx & 31;
            int o = (lr >> 5) * 64 + 32 * pass + (lr & 31);
            float val = obuf[lr * 33 + px];
            size_t oi = ((size_t)(batch * NO + o) << 14) + plocal0 + px;
            if (isf32) ((float*)out)[oi] = val;
            else       ((ushort_t*)out)[oi] = f2bf(val);
        }
        __syncthreads();
    }
}

// ---------------------------------------------------------------------------
extern "C" void kernel_launch(void* const* d_in, const int* in_sizes, int n_in,
                              void* d_out, int out_size, void* d_ws, size_t ws_size,
                              hipStream_t stream) {
    const void* x      = d_in[0];
    const void* w1     = d_in[1];
    const void* b1     = d_in[2];
    const void* w2     = d_in[3];
    const void* b2     = d_in[4];
    const void* ln1w   = d_in[5];
    const void* ln1b   = d_in[6];
    const void* conv_w = d_in[7];
    const void* ln2w   = d_in[8];
    const void* ln2b   = d_in[9];
    const void* map_w  = d_in[10];
    const void* map_b  = d_in[11];
    const void* ln3w   = d_in[12];
    const void* ln3b   = d_in[13];

    char* ws = (char*)d_ws;
    ushort_t* xT    = (ushort_t*)(ws);                  // 16,777,216 B
    ushort_t* y1    = (ushort_t*)(ws + 16777216);       // 16,777,216 B
    ushort_t* wcb   = (ushort_t*)(ws + 33554432);       //  65,536 B
    ushort_t* wmb   = (ushort_t*)(ws + 33619968);       //  65,536 B
    ushort_t* w1b   = (ushort_t*)(ws + 33685504);       //   8,192 B
    ushort_t* w2b   = (ushort_t*)(ws + 33693696);       //  25,600 B
    float*    b1f   = (float*)(ws + 33719296);
    float*    b2f   = (float*)(ws + 33719424);
    float*    ln1wf = (float*)(ws + 33721024);
    float*    ln1bf = (float*)(ws + 33721536);
    float*    mbf   = (float*)(ws + 33722048);
    float*    ln2wf = (float*)(ws + 33723072);
    float*    ln2bf = (float*)(ws + 33724096);
    float*    ln3wf = (float*)(ws + 33725120);
    float*    ln3bf = (float*)(ws + 33726144);
    int*      flag  = (int*)(ws + 33727168);
    const size_t NEED_SMALL = 33727184;
    ushort_t* wkT   = (ushort_t*)(ws + 33727232);       // 52,428,800 B
    const size_t NEED_BIG = 33727232 + (size_t)NKP * NPIX * 2;   // ~86.2 MB

    if (ws_size < NEED_SMALL) {
        int nwords = out_size / 2;
        ksentinel<<<(nwords + 255) / 256, 256, 0, stream>>>((uint_t*)d_out, nwords);
        return;
    }

    kdetect<<<1, 64, 0, stream>>>((const uint_t*)x, flag);
    kprep<<<128, 256, 0, stream>>>(w1, w2, conv_w, map_w, b1, b2, ln1w, ln1b,
                                   ln2w, ln2b, map_b, ln3w, ln3b, flag,
                                   w1b, w2b, wcb, wmb, b1f, b2f, ln1wf, ln1bf,
                                   ln2wf, ln2bf, mbf, ln3wf, ln3bf);
    ktrans<<<dim3(8, 128, 4), 256, 0, stream>>>(x, xT, flag);

    if (ws_size >= NEED_BIG) {
        k1a<<<1024, 256, 0, stream>>>(xT, w1b, b1f, w2b, b2f, wkT);
        k1b<<<1024, 256, 0, stream>>>(xT, wkT, ln1wf, ln1bf, y1);
    } else {
        k1_fused<<<dim3(16, 64, 4), 64, 0, stream>>>(xT, w1b, b1f, w2b, b2f,
                                                     ln1wf, ln1bf, y1);
    }

    k23<<<NPIX / 32, 256, 0, stream>>>(y1, xT, wcb, wmb, mbf,
                                       ln2wf, ln2bf, ln3wf, ln3bf, d_out, flag);
}

// Round 7
// 306.105 us; speedup vs baseline: 3.2974x; 1.1242x over previous
//
#include <hip/hip_runtime.h>

typedef unsigned short ushort_t;
typedef unsigned int uint_t;

#define NB 4
#define NC 128
#define NH 128
#define NW 128
#define NPIX 65536   // NB*NH*NW
#define NMID 32
#define NKK 49
#define NK 392
#define NKP 400      // NK padded to 25 n-tiles of 16
#define NO 256
#define LN_EPS 1e-6f

typedef __attribute__((ext_vector_type(8))) short short8;
typedef __attribute__((ext_vector_type(4))) float floatx4;

__device__ __forceinline__ float bf2f(ushort_t u) {
    union { uint_t i; float f; } v; v.i = ((uint_t)u) << 16; return v.f;
}
__device__ __forceinline__ ushort_t f2bf(float f) {
    union { float f; uint_t i; } v; v.f = f;
    uint_t x = v.i;
    uint_t r = (x + 0x7FFFu + ((x >> 16) & 1u)) >> 16;
    return (ushort_t)r;
}
__device__ __forceinline__ float gelu_f(float x) {
    return 0.5f * x * (1.0f + erff(x * 0.70710678118654752f));
}
__device__ __forceinline__ float ldin(const void* p, int i, int isf32) {
    return isf32 ? ((const float*)p)[i] : bf2f(((const ushort_t*)p)[i]);
}

// ---------------------------------------------------------------------------
__global__ void kdetect(const uint_t* __restrict__ xw, int* __restrict__ flag) {
    int lane = threadIdx.x;
    int cnt = 0;
    for (int j = 0; j < 8; j++) {
        uint_t w = xw[lane * 8 + j];
        uint_t e = (w >> 7) & 0xffu;
        if (e >= 110u && e <= 135u) cnt++;
    }
    for (int d = 1; d < 64; d <<= 1) cnt += __shfl_xor(cnt, d);
    if (lane == 0) flag[0] = (cnt < 256) ? 1 : 0;
}

__global__ void ksentinel(uint_t* __restrict__ out, int nwords) {
    int i = blockIdx.x * 256 + threadIdx.x;
    if (i < nwords) out[i] = 0x40004000u;
}

// ---------------------------------------------------------------------------
// K0a: transpose x (B,C,H,W) -> xT (B,H,W,C) canonical bf16.
// ---------------------------------------------------------------------------
__global__ __launch_bounds__(256) void ktrans(const void* __restrict__ x,
                                              ushort_t* __restrict__ xT,
                                              const int* __restrict__ flag) {
    int isf32 = flag[0];
    int b = blockIdx.z, h = blockIdx.y;
    int wchunk = blockIdx.x & 1, cchunk = blockIdx.x >> 1;
    int w0 = wchunk << 6, c0 = cchunk << 5;
    __shared__ ushort_t tile[32][66];
    int tx = threadIdx.x & 63, ty = threadIdx.x >> 6;
    for (int r = 0; r < 32; r += 4) {
        int idx = (((b * NC + c0 + r + ty) * NH) + h) * NW + w0 + tx;
        tile[r + ty][tx] = isf32 ? f2bf(((const float*)x)[idx])
                                 : ((const ushort_t*)x)[idx];
    }
    __syncthreads();
    int cc = threadIdx.x & 31, wq = threadIdx.x >> 5;
    for (int pp = 0; pp < 64; pp += 8) {
        int wx = pp + wq;
        xT[((size_t)((b * NH + h) * NW) + w0 + wx) * NC + c0 + cc] = tile[cc][wx];
    }
}

// ---------------------------------------------------------------------------
// K0b: param prep.
// ---------------------------------------------------------------------------
__global__ __launch_bounds__(256) void kprep(const void* w1, const void* w2,
                                             const void* conv_w, const void* map_w,
                                             const void* b1, const void* b2,
                                             const void* ln1w, const void* ln1b,
                                             const void* ln2w, const void* ln2b,
                                             const void* map_b,
                                             const void* ln3w, const void* ln3b,
                                             const int* __restrict__ flag,
                                             ushort_t* __restrict__ w1b,
                                             ushort_t* __restrict__ w2b,
                                             ushort_t* __restrict__ wcb,
                                             ushort_t* __restrict__ wmb,
                                             float* __restrict__ b1f,
                                             float* __restrict__ b2f,
                                             float* __restrict__ ln1wf,
                                             float* __restrict__ ln1bf,
                                             float* __restrict__ ln2wf,
                                             float* __restrict__ ln2bf,
                                             float* __restrict__ mbf,
                                             float* __restrict__ ln3wf,
                                             float* __restrict__ ln3bf) {
    int isf32 = flag[0];
    int i = blockIdx.x * 256 + threadIdx.x;
    if (i < NMID * NC) w1b[i] = f2bf(ldin(w1, i, isf32));
    if (i < NKP * NMID) w2b[i] = (i < NK * NMID) ? f2bf(ldin(w2, i, isf32))
                                                 : (ushort_t)0;
    wcb[i] = f2bf(ldin(conv_w, i, isf32));
    wmb[i] = f2bf(ldin(map_w, i, isf32));
    if (i < NMID) b1f[i] = ldin(b1, i, isf32);
    if (i < NKP)  b2f[i] = (i < NK) ? ldin(b2, i, isf32) : 0.f;
    if (i < NC) { ln1wf[i] = ldin(ln1w, i, isf32); ln1bf[i] = ldin(ln1b, i, isf32); }
    if (i < NO) {
        ln2wf[i] = ldin(ln2w, i, isf32); ln2bf[i] = ldin(ln2b, i, isf32);
        mbf[i]   = ldin(map_b, i, isf32);
        ln3wf[i] = ldin(ln3w, i, isf32); ln3bf[i] = ldin(ln3b, i, isf32);
    }
}

// ---------------------------------------------------------------------------
// K1a: wk producer (unchanged). grid 1024, block 256.
// ---------------------------------------------------------------------------
__global__ __launch_bounds__(256) void k1a(const ushort_t* __restrict__ xT,
                                           const ushort_t* __restrict__ w1b,
                                           const float* __restrict__ b1f,
                                           const ushort_t* __restrict__ w2b,
                                           const float* __restrict__ b2f,
                                           ushort_t* __restrict__ wkT) {
    __shared__ ushort_t midbuf[64 * 32];
    __shared__ ushort_t wkstage[NKP * 66];

    int t = threadIdx.x;
    int lane = t & 63;
    int w = __builtin_amdgcn_readfirstlane(t >> 6);
    int l16 = lane & 15, quad = lane >> 4;
    int tileid = blockIdx.x;
    int tilex = tileid & 15, tiley = (tileid >> 4) & 15, b = tileid >> 8;
    int h0 = tiley * 8, w0 = tilex * 8;

    int lpx_a = 16 * w + l16;
    int py = lpx_a >> 3, pxx = lpx_a & 7;
    const ushort_t* abase = xT + (size_t)((b * NH + h0 + py) * NW + w0 + pxx) * NC + quad * 8;
    floatx4 am0 = (floatx4)0.f, am1 = (floatx4)0.f;
#pragma unroll
    for (int kb = 0; kb < 4; kb++) {
        short8 a   = *(const short8*)(abase + kb * 32);
        short8 b0  = *(const short8*)(w1b + (l16) * NC + kb * 32 + quad * 8);
        short8 b1v = *(const short8*)(w1b + (16 + l16) * NC + kb * 32 + quad * 8);
        am0 = __builtin_amdgcn_mfma_f32_16x16x32_bf16(a, b0, am0, 0, 0, 0);
        am1 = __builtin_amdgcn_mfma_f32_16x16x32_bf16(a, b1v, am1, 0, 0, 0);
    }
    {
        float bia0 = b1f[l16], bia1 = b1f[16 + l16];
#pragma unroll
        for (int r = 0; r < 4; r++) {
            int m = 16 * w + quad * 4 + r;
            midbuf[m * 32 + l16]      = f2bf(fmaxf(am0[r] + bia0, 0.f));
            midbuf[m * 32 + 16 + l16] = f2bf(fmaxf(am1[r] + bia1, 0.f));
        }
    }
    __syncthreads();

    short8 aM = *(const short8*)(midbuf + (16 * w + l16) * 32 + quad * 8);
#pragma unroll
    for (int nt = 0; nt < 25; nt++) {
        int n = nt * 16 + l16;
        short8 bw = *(const short8*)(w2b + n * 32 + quad * 8);
        floatx4 c = __builtin_amdgcn_mfma_f32_16x16x32_bf16(aM, bw, (floatx4)0.f, 0, 0, 0);
        float bias = b2f[n];
#pragma unroll
        for (int r = 0; r < 4; r++)
            wkstage[n * 66 + 16 * w + quad * 4 + r] = f2bf(c[r] + bias);
    }
    __syncthreads();

    int krow = t >> 5, px2 = t & 31;
    for (int it = 0; it < 50; it++) {
        int k = it * 8 + krow;
        uint_t v = *(const uint_t*)&wkstage[k * 66 + 2 * px2];
        *(uint_t*)&wkT[(size_t)k * NPIX + tileid * 64 + 2 * px2] = v;
    }
}

// ---------------------------------------------------------------------------
// K1b v2: involution + LN + GELU, lane = pixel. Block 256 (4 waves), tile 8x8.
// TWO channel phases (64 ch each) reuse one halo buffer: LDS 27.3 KB.
// Halo as uint2 [cquad16][hp 196 pad 197]: ds_read_b64 yields 4 channels.
// Wave w + phase p <=> involution group g = 4p+w; its 49 wk taps preloaded
// (packed bf16) before staging so global latency overlaps the LDS fill.
// grid 1024.
// ---------------------------------------------------------------------------
__global__ __launch_bounds__(256) void k1b(const ushort_t* __restrict__ xT,
                                           const ushort_t* __restrict__ wkT,
                                           const float* __restrict__ ln1wf,
                                           const float* __restrict__ ln1bf,
                                           ushort_t* __restrict__ y1) {
    __shared__ uint2 x4[16 * 197];           // 25,216 B
    __shared__ float sred[4][64][2];         //  2,048 B

    int t = threadIdx.x;
    int lane = t & 63;
    int w = __builtin_amdgcn_readfirstlane(t >> 6);
    int tileid = blockIdx.x;
    int tilex = tileid & 15, tiley = (tileid >> 4) & 15, b = tileid >> 8;
    int h0 = tiley * 8, w0 = tilex * 8;
    int py = lane >> 3, pxx = lane & 7;
    int base0 = py * 14 + pxx;

    float a[32];
#pragma unroll
    for (int j = 0; j < 32; j++) a[j] = 0.f;

#pragma unroll
    for (int p = 0; p < 2; p++) {
        if (p) __syncthreads();              // protect phase-0 reads

        // ---- preload this phase's 49 wk taps (group g = 4p+w), packed bf16
        int g = 4 * p + w;
        const ushort_t* wkbase = wkT + (size_t)(g * NKK) * NPIX + tileid * 64 + lane;
        uint_t wkp[25];
#pragma unroll
        for (int j = 0; j < 24; j++) {
            uint_t lo = wkbase[(size_t)(2 * j) * NPIX];
            uint_t hi = wkbase[(size_t)(2 * j + 1) * NPIX];
            wkp[j] = lo | (hi << 16);
        }
        wkp[24] = wkbase[(size_t)48 * NPIX];

        // ---- stage halo for channels [64p, 64p+64): 16 cquads x 196 hp ----
        for (int it = 0; it < 13; it++) {
            int idx = it * 256 + t;
            if (idx < 3136) {
                int q = idx & 15, hp = idx >> 4;
                int hy = hp / 14, hx = hp - hy * 14;
                int gh = h0 + hy - 3, gw = w0 + hx - 3;
                uint2 v = make_uint2(0u, 0u);
                if ((unsigned)gh < (unsigned)NH && (unsigned)gw < (unsigned)NW) {
                    v = *(const uint2*)&xT[(size_t)((b * NH + gh) * NW + gw) * NC
                                           + 64 * p + 4 * q];
                }
                x4[q * 197 + hp] = v;
            }
        }
        __syncthreads();

        // ---- compute: 49 taps x 4 cquads (wave w owns cquads [4w,4w+4)) ----
#pragma unroll
        for (int tap = 0; tap < NKK; tap++) {
            float wkf = (tap & 1) ? bf2f((ushort_t)(wkp[tap >> 1] >> 16))
                                  : bf2f((ushort_t)(wkp[tap >> 1] & 0xffffu));
            int xa = base0 + (tap / 7) * 14 + (tap % 7);
#pragma unroll
            for (int q = 0; q < 4; q++) {
                uint2 u = x4[(4 * w + q) * 197 + xa];
                float x0 = bf2f((ushort_t)(u.x & 0xffffu));
                float x1 = bf2f((ushort_t)(u.x >> 16));
                float x2v = bf2f((ushort_t)(u.y & 0xffffu));
                float x3 = bf2f((ushort_t)(u.y >> 16));
                int aj = p * 16 + q * 4;
                a[aj]     = fmaf(wkf, x0, a[aj]);
                a[aj + 1] = fmaf(wkf, x1, a[aj + 1]);
                a[aj + 2] = fmaf(wkf, x2v, a[aj + 2]);
                a[aj + 3] = fmaf(wkf, x3, a[aj + 3]);
            }
        }
    }

    // ---- LN over 128 channels: per-px cross-wave reduce ----
    float s = 0.f, sq = 0.f;
#pragma unroll
    for (int j = 0; j < 32; j++) { s += a[j]; sq += a[j] * a[j]; }
    sred[w][lane][0] = s; sred[w][lane][1] = sq;
    __syncthreads();
    float ts = 0.f, tq = 0.f;
#pragma unroll
    for (int r = 0; r < 4; r++) { ts += sred[r][lane][0]; tq += sred[r][lane][1]; }
    float mean = ts * (1.0f / NC);
    float var = tq * (1.0f / NC) - mean * mean;
    float rstd = rsqrtf(var + LN_EPS);

    size_t pglob = (size_t)((b * NH + h0 + py) * NW + w0 + pxx);
    uint_t* yrow = (uint_t*)(y1 + pglob * NC);
#pragma unroll
    for (int p = 0; p < 2; p++) {
#pragma unroll
        for (int j = 0; j < 8; j++) {
            int c0 = p * 64 + 16 * w + 2 * j;
            float g0 = gelu_f((a[p * 16 + 2 * j] - mean) * rstd * ln1wf[c0] + ln1bf[c0]);
            float g1 = gelu_f((a[p * 16 + 2 * j + 1] - mean) * rstd * ln1wf[c0 + 1] + ln1bf[c0 + 1]);
            yrow[c0 >> 1] = (uint_t)f2bf(g0) | ((uint_t)f2bf(g1) << 16);
        }
    }
}

// ---------------------------------------------------------------------------
// K1 fused fallback — used only if ws too small for wkT.
// ---------------------------------------------------------------------------
__global__ __launch_bounds__(64) void k1_fused(const ushort_t* __restrict__ xT,
                                               const ushort_t* __restrict__ w1b,
                                               const float* __restrict__ b1f,
                                               const ushort_t* __restrict__ w2b,
                                               const float* __restrict__ b2f,
                                               const float* __restrict__ ln1wf,
                                               const float* __restrict__ ln1bf,
                                               ushort_t* __restrict__ y1) {
    __shared__ ushort_t midbuf[16 * 32];
    __shared__ ushort_t wkbuf[16 * NKP];

    int lane = threadIdx.x;
    int l16 = lane & 15, quad = lane >> 4;
    int b = blockIdx.z;
    int h0 = blockIdx.y * 2, w0 = blockIdx.x * 8;

    int Pa = (b * NH + h0 + (l16 >> 3)) * NW + w0 + (l16 & 7);
    const ushort_t* abase = xT + (size_t)Pa * NC + quad * 8;
    floatx4 am0 = (floatx4)0.f, am1 = (floatx4)0.f;
#pragma unroll
    for (int kb = 0; kb < 4; kb++) {
        short8 a   = *(const short8*)(abase + kb * 32);
        short8 b0  = *(const short8*)(w1b + (l16) * NC + kb * 32 + quad * 8);
        short8 b1v = *(const short8*)(w1b + (16 + l16) * NC + kb * 32 + quad * 8);
        am0 = __builtin_amdgcn_mfma_f32_16x16x32_bf16(a, b0, am0, 0, 0, 0);
        am1 = __builtin_amdgcn_mfma_f32_16x16x32_bf16(a, b1v, am1, 0, 0, 0);
    }
    {
        float bia0 = b1f[l16], bia1 = b1f[16 + l16];
#pragma unroll
        for (int r = 0; r < 4; r++) {
            int m = quad * 4 + r;
            midbuf[m * 32 + l16]      = f2bf(fmaxf(am0[r] + bia0, 0.f));
            midbuf[m * 32 + 16 + l16] = f2bf(fmaxf(am1[r] + bia1, 0.f));
        }
    }
    __syncthreads();

    short8 aM = *(const short8*)(midbuf + l16 * 32 + quad * 8);
#pragma unroll
    for (int nt = 0; nt < 25; nt++) {
        int n = nt * 16 + l16;
        short8 bw = *(const short8*)(w2b + n * 32 + quad * 8);
        floatx4 c = __builtin_amdgcn_mfma_f32_16x16x32_bf16(aM, bw, (floatx4)0.f, 0, 0, 0);
        float bias = b2f[n];
#pragma unroll
        for (int r = 0; r < 4; r++)
            wkbuf[(quad * 4 + r) * NKP + n] = f2bf(c[r] + bias);
    }
    __syncthreads();

    int g = lane >> 3;
    float l1w0 = ln1wf[2 * lane], l1w1 = ln1wf[2 * lane + 1];
    float l1b0 = ln1bf[2 * lane], l1b1 = ln1bf[2 * lane + 1];

    for (int i = 0; i < 16; i++) {
        int hh0 = h0 + (i >> 3), ww0 = w0 + (i & 7);
        int p = (b * NH + hh0) * NW + ww0;
        const ushort_t* wkrow = wkbuf + i * NKP + g * NKK;
        float a0 = 0.f, a1 = 0.f;
#pragma unroll
        for (int dy = -3; dy <= 3; dy++) {
            int hh = hh0 + dy;
            if ((unsigned)hh >= (unsigned)NH) continue;
#pragma unroll
            for (int dx = -3; dx <= 3; dx++) {
                int ww = ww0 + dx;
                if ((unsigned)ww >= (unsigned)NW) continue;
                float wkv = bf2f(wkrow[(dy + 3) * 7 + (dx + 3)]);
                uint_t xp = *(const uint_t*)(xT + ((size_t)(p + dy * NW + dx)) * NC + 2 * lane);
                a0 = fmaf(wkv, bf2f((ushort_t)(xp & 0xffffu)), a0);
                a1 = fmaf(wkv, bf2f((ushort_t)(xp >> 16)), a1);
            }
        }
        float s = a0 + a1, sq = a0 * a0 + a1 * a1;
#pragma unroll
        for (int d = 1; d < 64; d <<= 1) {
            s  += __shfl_xor(s, d);
            sq += __shfl_xor(sq, d);
        }
        float mean = s * (1.0f / NC);
        float var = sq * (1.0f / NC) - mean * mean;
        float rstd = rsqrtf(var + LN_EPS);
        float g0 = gelu_f((a0 - mean) * rstd * l1w0 + l1b0);
        float g1 = gelu_f((a1 - mean) * rstd * l1w1 + l1b1);
        uint_t pk = (uint_t)f2bf(g0) | ((uint_t)f2bf(g1) << 16);
        *(uint_t*)(y1 + (size_t)p * NC + 2 * lane) = pk;
    }
}

// ---------------------------------------------------------------------------
// K23 (unchanged).
// ---------------------------------------------------------------------------
__global__ __launch_bounds__(256) void k23(const ushort_t* __restrict__ y1,
                                           const ushort_t* __restrict__ xT,
                                           const ushort_t* __restrict__ wcb,
                                           const ushort_t* __restrict__ wmb,
                                           const float* __restrict__ mbf,
                                           const float* __restrict__ ln2wf,
                                           const float* __restrict__ ln2bf,
                                           const float* __restrict__ ln3wf,
                                           const float* __restrict__ ln3bf,
                                           void* __restrict__ out,
                                           const int* __restrict__ flag) {
    __shared__ __align__(16) char smem[19456];
    ushort_t* ybufF = (ushort_t*)smem;
    ushort_t* xbufF = (ushort_t*)(smem + 8192);
    float*    obuf  = (float*)smem;
    float*    sred  = (float*)(smem + 16896);
    float*    sstat = (float*)(smem + 18944);

    int isf32 = flag[0];
    int t = threadIdx.x;
    int P0 = blockIdx.x * 32;

    for (int rep = 0; rep < 2; rep++) {
        int q = rep * 256 + t;
        int pl = q & 15, quad_ = (q >> 4) & 3, kb = (q >> 6) & 3, mt = (q >> 8) & 1;
        int p = mt * 16 + pl;
        int c0 = kb * 32 + quad_ * 8;
        size_t src = (size_t)(P0 + p) * NC + c0;
        int dst = ((mt * 4 + kb) * 64 + quad_ * 16 + pl) * 8;
        *(uint4*)&ybufF[dst] = *(const uint4*)&y1[src];
        *(uint4*)&xbufF[dst] = *(const uint4*)&xT[src];
    }
    __syncthreads();

    int lane = t & 63;
    int w = __builtin_amdgcn_readfirstlane(t >> 6);
    int quad = lane >> 4;
    int l16 = lane & 15;

    floatx4 accC[2][4], accM[2][4];
#pragma unroll
    for (int mt = 0; mt < 2; mt++)
#pragma unroll
        for (int nt = 0; nt < 4; nt++) {
            accC[mt][nt] = (floatx4)0.0f;
            accM[mt][nt] = (floatx4)0.0f;
        }

#pragma unroll
    for (int kb = 0; kb < 4; kb++) {
        short8 aY0 = *(const short8*)&ybufF[((0 * 4 + kb) * 64 + lane) * 8];
        short8 aY1 = *(const short8*)&ybufF[((1 * 4 + kb) * 64 + lane) * 8];
        short8 aX0 = *(const short8*)&xbufF[((0 * 4 + kb) * 64 + lane) * 8];
        short8 aX1 = *(const short8*)&xbufF[((1 * 4 + kb) * 64 + lane) * 8];
#pragma unroll
        for (int nt = 0; nt < 4; nt++) {
            int o = w * 64 + nt * 16 + l16;
            size_t boff = (size_t)o * NC + kb * 32 + quad * 8;
            short8 bc = *(const short8*)&wcb[boff];
            short8 bm = *(const short8*)&wmb[boff];
            accC[0][nt] = __builtin_amdgcn_mfma_f32_16x16x32_bf16(aY0, bc, accC[0][nt], 0, 0, 0);
            accC[1][nt] = __builtin_amdgcn_mfma_f32_16x16x32_bf16(aY1, bc, accC[1][nt], 0, 0, 0);
            accM[0][nt] = __builtin_amdgcn_mfma_f32_16x16x32_bf16(aX0, bm, accM[0][nt], 0, 0, 0);
            accM[1][nt] = __builtin_amdgcn_mfma_f32_16x16x32_bf16(aX1, bm, accM[1][nt], 0, 0, 0);
        }
    }

    float mb_[4], l2w_[4], l2b_[4], l3w_[4], l3b_[4];
#pragma unroll
    for (int nt = 0; nt < 4; nt++) {
        int o = w * 64 + nt * 16 + l16;
        mb_[nt] = mbf[o];
        l2w_[nt] = ln2wf[o]; l2b_[nt] = ln2bf[o];
        l3w_[nt] = ln3wf[o]; l3b_[nt] = ln3bf[o];
    }
#pragma unroll
    for (int mt = 0; mt < 2; mt++)
#pragma unroll
        for (int nt = 0; nt < 4; nt++)
#pragma unroll
            for (int r = 0; r < 4; r++)
                accM[mt][nt][r] += mb_[nt];

#pragma unroll
    for (int mt = 0; mt < 2; mt++) {
#pragma unroll
        for (int r = 0; r < 4; r++) {
            float s1 = 0.f, s1q = 0.f, s2 = 0.f, s2q = 0.f;
#pragma unroll
            for (int nt = 0; nt < 4; nt++) {
                float a = accC[mt][nt][r], m = accM[mt][nt][r];
                s1 += a; s1q += a * a; s2 += m; s2q += m * m;
            }
#pragma unroll
            for (int d = 1; d < 16; d <<= 1) {
                s1  += __shfl_xor(s1, d);
                s1q += __shfl_xor(s1q, d);
                s2  += __shfl_xor(s2, d);
                s2q += __shfl_xor(s2q, d);
            }
            if (l16 == 0) {
                int px = mt * 16 + quad * 4 + r;
                float* sp = sred + ((w * 32 + px) * 4);
                sp[0] = s1; sp[1] = s1q; sp[2] = s2; sp[3] = s2q;
            }
        }
    }
    __syncthreads();

    if (t < 32) {
        float a0 = 0.f, a1 = 0.f, a2 = 0.f, a3 = 0.f;
        for (int ww = 0; ww < 4; ww++) {
            const float* sp = sred + ((ww * 32 + t) * 4);
            a0 += sp[0]; a1 += sp[1]; a2 += sp[2]; a3 += sp[3];
        }
        float m1 = a0 * (1.0f / NO);
        float v1 = a1 * (1.0f / NO) - m1 * m1;
        float m2 = a2 * (1.0f / NO);
        float v2 = a3 * (1.0f / NO) - m2 * m2;
        float* st = sstat + t * 4;
        st[0] = m1; st[1] = rsqrtf(v1 + LN_EPS);
        st[2] = m2; st[3] = rsqrtf(v2 + LN_EPS);
    }
    __syncthreads();

    int batch = P0 >> 14;
    int plocal0 = P0 & 16383;
#pragma unroll
    for (int pass = 0; pass < 2; pass++) {
#pragma unroll
        for (int ntl = 0; ntl < 2; ntl++) {
            int nt = 2 * pass + ntl;
#pragma unroll
            for (int mt = 0; mt < 2; mt++) {
#pragma unroll
                for (int r = 0; r < 4; r++) {
                    int px = mt * 16 + quad * 4 + r;
                    const float* st = sstat + px * 4;
                    float v1 = (accC[mt][nt][r] - st[0]) * st[1] * l2w_[nt] + l2b_[nt];
                    float v2 = (accM[mt][nt][r] - st[2]) * st[3] * l3w_[nt] + l3b_[nt];
                    obuf[(w * 32 + ntl * 16 + l16) * 33 + px] = gelu_f(v1 + v2);
                }
            }
        }
        __syncthreads();
        for (int it = 0; it < 16; it++) {
            int idx = it * 256 + t;
            int lr = idx >> 5, px = idx & 31;
            int o = (lr >> 5) * 64 + 32 * pass + (lr & 31);
            float val = obuf[lr * 33 + px];
            size_t oi = ((size_t)(batch * NO + o) << 14) + plocal0 + px;
            if (isf32) ((float*)out)[oi] = val;
            else       ((ushort_t*)out)[oi] = f2bf(val);
        }
        __syncthreads();
    }
}

// ---------------------------------------------------------------------------
extern "C" void kernel_launch(void* const* d_in, const int* in_sizes, int n_in,
                              void* d_out, int out_size, void* d_ws, size_t ws_size,
                              hipStream_t stream) {
    const void* x      = d_in[0];
    const void* w1     = d_in[1];
    const void* b1     = d_in[2];
    const void* w2     = d_in[3];
    const void* b2     = d_in[4];
    const void* ln1w   = d_in[5];
    const void* ln1b   = d_in[6];
    const void* conv_w = d_in[7];
    const void* ln2w   = d_in[8];
    const void* ln2b   = d_in[9];
    const void* map_w  = d_in[10];
    const void* map_b  = d_in[11];
    const void* ln3w   = d_in[12];
    const void* ln3b   = d_in[13];

    char* ws = (char*)d_ws;
    ushort_t* xT    = (ushort_t*)(ws);                  // 16,777,216 B
    ushort_t* y1    = (ushort_t*)(ws + 16777216);       // 16,777,216 B
    ushort_t* wcb   = (ushort_t*)(ws + 33554432);       //  65,536 B
    ushort_t* wmb   = (ushort_t*)(ws + 33619968);       //  65,536 B
    ushort_t* w1b   = (ushort_t*)(ws + 33685504);       //   8,192 B
    ushort_t* w2b   = (ushort_t*)(ws + 33693696);       //  25,600 B
    float*    b1f   = (float*)(ws + 33719296);
    float*    b2f   = (float*)(ws + 33719424);
    float*    ln1wf = (float*)(ws + 33721024);
    float*    ln1bf = (float*)(ws + 33721536);
    float*    mbf   = (float*)(ws + 33722048);
    float*    ln2wf = (float*)(ws + 33723072);
    float*    ln2bf = (float*)(ws + 33724096);
    float*    ln3wf = (float*)(ws + 33725120);
    float*    ln3bf = (float*)(ws + 33726144);
    int*      flag  = (int*)(ws + 33727168);
    const size_t NEED_SMALL = 33727184;
    ushort_t* wkT   = (ushort_t*)(ws + 33727232);       // 52,428,800 B
    const size_t NEED_BIG = 33727232 + (size_t)NKP * NPIX * 2;   // ~86.2 MB

    if (ws_size < NEED_SMALL) {
        int nwords = out_size / 2;
        ksentinel<<<(nwords + 255) / 256, 256, 0, stream>>>((uint_t*)d_out, nwords);
        return;
    }

    kdetect<<<1, 64, 0, stream>>>((const uint_t*)x, flag);
    kprep<<<128, 256, 0, stream>>>(w1, w2, conv_w, map_w, b1, b2, ln1w, ln1b,
                                   ln2w, ln2b, map_b, ln3w, ln3b, flag,
                                   w1b, w2b, wcb, wmb, b1f, b2f, ln1wf, ln1bf,
                                   ln2wf, ln2bf, mbf, ln3wf, ln3bf);
    ktrans<<<dim3(8, 128, 4), 256, 0, stream>>>(x, xT, flag);

    if (ws_size >= NEED_BIG) {
        k1a<<<1024, 256, 0, stream>>>(xT, w1b, b1f, w2b, b2f, wkT);
        k1b<<<1024, 256, 0, stream>>>(xT, wkT, ln1wf, ln1bf, y1);
    } else {
        k1_fused<<<dim3(16, 64, 4), 64, 0, stream>>>(xT, w1b, b1f, w2b, b2f,
                                                     ln1wf, ln1bf, y1);
    }

    k23<<<NPIX / 32, 256, 0, stream>>>(y1, xT, wcb, wmb, mbf,
                                       ln2wf, ln2bf, ln3wf, ln3bf, d_out, flag);
}

// Round 8
// 262.525 us; speedup vs baseline: 3.8447x; 1.1660x over previous
//
#include <hip/hip_runtime.h>

typedef unsigned short ushort_t;
typedef unsigned int uint_t;

#define NB 4
#define NC 128
#define NH 128
#define NW 128
#define NPIX 65536   // NB*NH*NW
#define NMID 32
#define NKK 49
#define NK 392
#define NKP 400      // NK padded to 25 n-tiles of 16
#define NO 256
#define LN_EPS 1e-6f

typedef __attribute__((ext_vector_type(8))) short short8;
typedef __attribute__((ext_vector_type(4))) float floatx4;

__device__ __forceinline__ float bf2f(ushort_t u) {
    union { uint_t i; float f; } v; v.i = ((uint_t)u) << 16; return v.f;
}
__device__ __forceinline__ float bf2f_lo(uint_t u) {
    union { uint_t i; float f; } v; v.i = u << 16; return v.f;
}
__device__ __forceinline__ float bf2f_hi(uint_t u) {
    union { uint_t i; float f; } v; v.i = u & 0xffff0000u; return v.f;
}
__device__ __forceinline__ ushort_t f2bf(float f) {
    union { float f; uint_t i; } v; v.f = f;
    uint_t x = v.i;
    uint_t r = (x + 0x7FFFu + ((x >> 16) & 1u)) >> 16;
    return (ushort_t)r;
}
__device__ __forceinline__ float gelu_f(float x) {
    return 0.5f * x * (1.0f + erff(x * 0.70710678118654752f));
}
__device__ __forceinline__ float ldin(const void* p, int i, int isf32) {
    return isf32 ? ((const float*)p)[i] : bf2f(((const ushort_t*)p)[i]);
}

// ---------------------------------------------------------------------------
__global__ void kdetect(const uint_t* __restrict__ xw, int* __restrict__ flag) {
    int lane = threadIdx.x;
    int cnt = 0;
    for (int j = 0; j < 8; j++) {
        uint_t w = xw[lane * 8 + j];
        uint_t e = (w >> 7) & 0xffu;
        if (e >= 110u && e <= 135u) cnt++;
    }
    for (int d = 1; d < 64; d <<= 1) cnt += __shfl_xor(cnt, d);
    if (lane == 0) flag[0] = (cnt < 256) ? 1 : 0;
}

__global__ void ksentinel(uint_t* __restrict__ out, int nwords) {
    int i = blockIdx.x * 256 + threadIdx.x;
    if (i < nwords) out[i] = 0x40004000u;
}

// ---------------------------------------------------------------------------
// K0a: transpose x (B,C,H,W) -> xT (B,H,W,C) canonical bf16.
// ---------------------------------------------------------------------------
__global__ __launch_bounds__(256) void ktrans(const void* __restrict__ x,
                                              ushort_t* __restrict__ xT,
                                              const int* __restrict__ flag) {
    int isf32 = flag[0];
    int b = blockIdx.z, h = blockIdx.y;
    int wchunk = blockIdx.x & 1, cchunk = blockIdx.x >> 1;
    int w0 = wchunk << 6, c0 = cchunk << 5;
    __shared__ ushort_t tile[32][66];
    int tx = threadIdx.x & 63, ty = threadIdx.x >> 6;
    for (int r = 0; r < 32; r += 4) {
        int idx = (((b * NC + c0 + r + ty) * NH) + h) * NW + w0 + tx;
        tile[r + ty][tx] = isf32 ? f2bf(((const float*)x)[idx])
                                 : ((const ushort_t*)x)[idx];
    }
    __syncthreads();
    int cc = threadIdx.x & 31, wq = threadIdx.x >> 5;
    for (int pp = 0; pp < 64; pp += 8) {
        int wx = pp + wq;
        xT[((size_t)((b * NH + h) * NW) + w0 + wx) * NC + c0 + cc] = tile[cc][wx];
    }
}

// ---------------------------------------------------------------------------
// K0b: param prep.
// ---------------------------------------------------------------------------
__global__ __launch_bounds__(256) void kprep(const void* w1, const void* w2,
                                             const void* conv_w, const void* map_w,
                                             const void* b1, const void* b2,
                                             const void* ln1w, const void* ln1b,
                                             const void* ln2w, const void* ln2b,
                                             const void* map_b,
                                             const void* ln3w, const void* ln3b,
                                             const int* __restrict__ flag,
                                             ushort_t* __restrict__ w1b,
                                             ushort_t* __restrict__ w2b,
                                             ushort_t* __restrict__ wcb,
                                             ushort_t* __restrict__ wmb,
                                             float* __restrict__ b1f,
                                             float* __restrict__ b2f,
                                             float* __restrict__ ln1wf,
                                             float* __restrict__ ln1bf,
                                             float* __restrict__ ln2wf,
                                             float* __restrict__ ln2bf,
                                             float* __restrict__ mbf,
                                             float* __restrict__ ln3wf,
                                             float* __restrict__ ln3bf) {
    int isf32 = flag[0];
    int i = blockIdx.x * 256 + threadIdx.x;
    if (i < NMID * NC) w1b[i] = f2bf(ldin(w1, i, isf32));
    if (i < NKP * NMID) w2b[i] = (i < NK * NMID) ? f2bf(ldin(w2, i, isf32))
                                                 : (ushort_t)0;
    wcb[i] = f2bf(ldin(conv_w, i, isf32));
    wmb[i] = f2bf(ldin(map_w, i, isf32));
    if (i < NMID) b1f[i] = ldin(b1, i, isf32);
    if (i < NKP)  b2f[i] = (i < NK) ? ldin(b2, i, isf32) : 0.f;
    if (i < NC) { ln1wf[i] = ldin(ln1w, i, isf32); ln1bf[i] = ldin(ln1b, i, isf32); }
    if (i < NO) {
        ln2wf[i] = ldin(ln2w, i, isf32); ln2bf[i] = ldin(ln2b, i, isf32);
        mbf[i]   = ldin(map_b, i, isf32);
        ln3wf[i] = ldin(ln3w, i, isf32); ln3bf[i] = ldin(ln3b, i, isf32);
    }
}

// ---------------------------------------------------------------------------
// K1a: wk producer (unchanged). grid 1024, block 256.
// ---------------------------------------------------------------------------
__global__ __launch_bounds__(256) void k1a(const ushort_t* __restrict__ xT,
                                           const ushort_t* __restrict__ w1b,
                                           const float* __restrict__ b1f,
                                           const ushort_t* __restrict__ w2b,
                                           const float* __restrict__ b2f,
                                           ushort_t* __restrict__ wkT) {
    __shared__ ushort_t midbuf[64 * 32];
    __shared__ ushort_t wkstage[NKP * 66];

    int t = threadIdx.x;
    int lane = t & 63;
    int w = __builtin_amdgcn_readfirstlane(t >> 6);
    int l16 = lane & 15, quad = lane >> 4;
    int tileid = blockIdx.x;
    int tilex = tileid & 15, tiley = (tileid >> 4) & 15, b = tileid >> 8;
    int h0 = tiley * 8, w0 = tilex * 8;

    int lpx_a = 16 * w + l16;
    int py = lpx_a >> 3, pxx = lpx_a & 7;
    const ushort_t* abase = xT + (size_t)((b * NH + h0 + py) * NW + w0 + pxx) * NC + quad * 8;
    floatx4 am0 = (floatx4)0.f, am1 = (floatx4)0.f;
#pragma unroll
    for (int kb = 0; kb < 4; kb++) {
        short8 a   = *(const short8*)(abase + kb * 32);
        short8 b0  = *(const short8*)(w1b + (l16) * NC + kb * 32 + quad * 8);
        short8 b1v = *(const short8*)(w1b + (16 + l16) * NC + kb * 32 + quad * 8);
        am0 = __builtin_amdgcn_mfma_f32_16x16x32_bf16(a, b0, am0, 0, 0, 0);
        am1 = __builtin_amdgcn_mfma_f32_16x16x32_bf16(a, b1v, am1, 0, 0, 0);
    }
    {
        float bia0 = b1f[l16], bia1 = b1f[16 + l16];
#pragma unroll
        for (int r = 0; r < 4; r++) {
            int m = 16 * w + quad * 4 + r;
            midbuf[m * 32 + l16]      = f2bf(fmaxf(am0[r] + bia0, 0.f));
            midbuf[m * 32 + 16 + l16] = f2bf(fmaxf(am1[r] + bia1, 0.f));
        }
    }
    __syncthreads();

    short8 aM = *(const short8*)(midbuf + (16 * w + l16) * 32 + quad * 8);
#pragma unroll
    for (int nt = 0; nt < 25; nt++) {
        int n = nt * 16 + l16;
        short8 bw = *(const short8*)(w2b + n * 32 + quad * 8);
        floatx4 c = __builtin_amdgcn_mfma_f32_16x16x32_bf16(aM, bw, (floatx4)0.f, 0, 0, 0);
        float bias = b2f[n];
#pragma unroll
        for (int r = 0; r < 4; r++)
            wkstage[n * 66 + 16 * w + quad * 4 + r] = f2bf(c[r] + bias);
    }
    __syncthreads();

    int krow = t >> 5, px2 = t & 31;
    for (int it = 0; it < 50; it++) {
        int k = it * 8 + krow;
        uint_t v = *(const uint_t*)&wkstage[k * 66 + 2 * px2];
        *(uint_t*)&wkT[(size_t)k * NPIX + tileid * 64 + 2 * px2] = v;
    }
}

// ---------------------------------------------------------------------------
// K1b v3: involution + LN + GELU. Block = 512 thr (8 waves), tile 8x8.
// wave = involution group (16 ch), lane = pixel. Halo as uint4 [oct16][hp197]
// -> ds_read_b128 with perfectly uniform banking (8/bank). sred overlaid on
// dead halo LDS. grid 1024.
// ---------------------------------------------------------------------------
__global__ __launch_bounds__(512) void k1b(const ushort_t* __restrict__ xT,
                                           const ushort_t* __restrict__ wkT,
                                           const float* __restrict__ ln1wf,
                                           const float* __restrict__ ln1bf,
                                           ushort_t* __restrict__ y1) {
    __shared__ __align__(16) char smem[50432];
    uint4* x8   = (uint4*)smem;              // [16 oct][197 hp]
    float* sred = (float*)smem;              // overlay after compute: [8][64][2]

    int t = threadIdx.x;
    int lane = t & 63;
    int w = __builtin_amdgcn_readfirstlane(t >> 6);   // wave id = group id
    int tileid = blockIdx.x;
    int tilex = tileid & 15, tiley = (tileid >> 4) & 15, b = tileid >> 8;
    int h0 = tiley * 8, w0 = tilex * 8;
    int py = lane >> 3, pxx = lane & 7;

    // ---- preload group w's 49 wk taps (packed bf16 pairs) ----
    const ushort_t* wkbase = wkT + (size_t)(w * NKK) * NPIX + tileid * 64 + lane;
    uint_t wkp[25];
#pragma unroll
    for (int j = 0; j < 24; j++) {
        uint_t lo = wkbase[(size_t)(2 * j) * NPIX];
        uint_t hi = wkbase[(size_t)(2 * j + 1) * NPIX];
        wkp[j] = lo | (hi << 16);
    }
    wkp[24] = wkbase[(size_t)48 * NPIX];

    // ---- stage full halo (128 ch): 196 hp x 16 octs of 8 ch ----
    for (int it = 0; it < 7; it++) {
        int idx = it * 512 + t;
        if (idx < 3136) {
            int oct = idx & 15, hp = idx >> 4;
            int hy = hp / 14, hx = hp - hy * 14;
            int gh = h0 + hy - 3, gw = w0 + hx - 3;
            uint4 v = make_uint4(0u, 0u, 0u, 0u);
            if ((unsigned)gh < (unsigned)NH && (unsigned)gw < (unsigned)NW) {
                v = *(const uint4*)&xT[(size_t)((b * NH + gh) * NW + gw) * NC + 8 * oct];
            }
            x8[oct * 197 + hp] = v;
        }
    }
    __syncthreads();

    // ---- involution: 49 taps x 16 channels (octs 2w, 2w+1) ----
    int base0 = py * 14 + pxx;
    float a[16];
#pragma unroll
    for (int j = 0; j < 16; j++) a[j] = 0.f;

#pragma unroll
    for (int tap = 0; tap < NKK; tap++) {
        float wkf = (tap & 1) ? bf2f((ushort_t)(wkp[tap >> 1] >> 16))
                              : bf2f((ushort_t)(wkp[tap >> 1] & 0xffffu));
        int xa = base0 + (tap / 7) * 14 + (tap % 7);
        uint4 u0 = x8[(2 * w) * 197 + xa];
        uint4 u1 = x8[(2 * w + 1) * 197 + xa];
        a[0]  = fmaf(wkf, bf2f_lo(u0.x), a[0]);
        a[1]  = fmaf(wkf, bf2f_hi(u0.x), a[1]);
        a[2]  = fmaf(wkf, bf2f_lo(u0.y), a[2]);
        a[3]  = fmaf(wkf, bf2f_hi(u0.y), a[3]);
        a[4]  = fmaf(wkf, bf2f_lo(u0.z), a[4]);
        a[5]  = fmaf(wkf, bf2f_hi(u0.z), a[5]);
        a[6]  = fmaf(wkf, bf2f_lo(u0.w), a[6]);
        a[7]  = fmaf(wkf, bf2f_hi(u0.w), a[7]);
        a[8]  = fmaf(wkf, bf2f_lo(u1.x), a[8]);
        a[9]  = fmaf(wkf, bf2f_hi(u1.x), a[9]);
        a[10] = fmaf(wkf, bf2f_lo(u1.y), a[10]);
        a[11] = fmaf(wkf, bf2f_hi(u1.y), a[11]);
        a[12] = fmaf(wkf, bf2f_lo(u1.z), a[12]);
        a[13] = fmaf(wkf, bf2f_hi(u1.z), a[13]);
        a[14] = fmaf(wkf, bf2f_lo(u1.w), a[14]);
        a[15] = fmaf(wkf, bf2f_hi(u1.w), a[15]);
    }
    __syncthreads();   // halo reads done; x8 region now dead -> reuse as sred

    // ---- LN over 128 ch: per-pixel reduce across 8 waves ----
    float s = 0.f, sq = 0.f;
#pragma unroll
    for (int j = 0; j < 16; j++) { s += a[j]; sq += a[j] * a[j]; }
    sred[(w * 64 + lane) * 2]     = s;
    sred[(w * 64 + lane) * 2 + 1] = sq;
    __syncthreads();
    float ts = 0.f, tq = 0.f;
#pragma unroll
    for (int r = 0; r < 8; r++) {
        ts += sred[(r * 64 + lane) * 2];
        tq += sred[(r * 64 + lane) * 2 + 1];
    }
    float mean = ts * (1.0f / NC);
    float var = tq * (1.0f / NC) - mean * mean;
    float rstd = rsqrtf(var + LN_EPS);

    // ---- GELU + write 16 ch (32 B = two uint4) ----
    int p = (b * NH + h0 + py) * NW + w0 + pxx;
    uint_t pk[8];
#pragma unroll
    for (int j = 0; j < 8; j++) {
        int c0 = 16 * w + 2 * j;
        float g0 = gelu_f((a[2 * j] - mean) * rstd * ln1wf[c0] + ln1bf[c0]);
        float g1 = gelu_f((a[2 * j + 1] - mean) * rstd * ln1wf[c0 + 1] + ln1bf[c0 + 1]);
        pk[j] = (uint_t)f2bf(g0) | ((uint_t)f2bf(g1) << 16);
    }
    uint4* dst = (uint4*)(y1 + (size_t)p * NC + 16 * w);
    dst[0] = make_uint4(pk[0], pk[1], pk[2], pk[3]);
    dst[1] = make_uint4(pk[4], pk[5], pk[6], pk[7]);
}

// ---------------------------------------------------------------------------
// K1 fused fallback — used only if ws too small for wkT.
// ---------------------------------------------------------------------------
__global__ __launch_bounds__(64) void k1_fused(const ushort_t* __restrict__ xT,
                                               const ushort_t* __restrict__ w1b,
                                               const float* __restrict__ b1f,
                                               const ushort_t* __restrict__ w2b,
                                               const float* __restrict__ b2f,
                                               const float* __restrict__ ln1wf,
                                               const float* __restrict__ ln1bf,
                                               ushort_t* __restrict__ y1) {
    __shared__ ushort_t midbuf[16 * 32];
    __shared__ ushort_t wkbuf[16 * NKP];

    int lane = threadIdx.x;
    int l16 = lane & 15, quad = lane >> 4;
    int b = blockIdx.z;
    int h0 = blockIdx.y * 2, w0 = blockIdx.x * 8;

    int Pa = (b * NH + h0 + (l16 >> 3)) * NW + w0 + (l16 & 7);
    const ushort_t* abase = xT + (size_t)Pa * NC + quad * 8;
    floatx4 am0 = (floatx4)0.f, am1 = (floatx4)0.f;
#pragma unroll
    for (int kb = 0; kb < 4; kb++) {
        short8 a   = *(const short8*)(abase + kb * 32);
        short8 b0  = *(const short8*)(w1b + (l16) * NC + kb * 32 + quad * 8);
        short8 b1v = *(const short8*)(w1b + (16 + l16) * NC + kb * 32 + quad * 8);
        am0 = __builtin_amdgcn_mfma_f32_16x16x32_bf16(a, b0, am0, 0, 0, 0);
        am1 = __builtin_amdgcn_mfma_f32_16x16x32_bf16(a, b1v, am1, 0, 0, 0);
    }
    {
        float bia0 = b1f[l16], bia1 = b1f[16 + l16];
#pragma unroll
        for (int r = 0; r < 4; r++) {
            int m = quad * 4 + r;
            midbuf[m * 32 + l16]      = f2bf(fmaxf(am0[r] + bia0, 0.f));
            midbuf[m * 32 + 16 + l16] = f2bf(fmaxf(am1[r] + bia1, 0.f));
        }
    }
    __syncthreads();

    short8 aM = *(const short8*)(midbuf + l16 * 32 + quad * 8);
#pragma unroll
    for (int nt = 0; nt < 25; nt++) {
        int n = nt * 16 + l16;
        short8 bw = *(const short8*)(w2b + n * 32 + quad * 8);
        floatx4 c = __builtin_amdgcn_mfma_f32_16x16x32_bf16(aM, bw, (floatx4)0.f, 0, 0, 0);
        float bias = b2f[n];
#pragma unroll
        for (int r = 0; r < 4; r++)
            wkbuf[(quad * 4 + r) * NKP + n] = f2bf(c[r] + bias);
    }
    __syncthreads();

    int g = lane >> 3;
    float l1w0 = ln1wf[2 * lane], l1w1 = ln1wf[2 * lane + 1];
    float l1b0 = ln1bf[2 * lane], l1b1 = ln1bf[2 * lane + 1];

    for (int i = 0; i < 16; i++) {
        int hh0 = h0 + (i >> 3), ww0 = w0 + (i & 7);
        int p = (b * NH + hh0) * NW + ww0;
        const ushort_t* wkrow = wkbuf + i * NKP + g * NKK;
        float a0 = 0.f, a1 = 0.f;
#pragma unroll
        for (int dy = -3; dy <= 3; dy++) {
            int hh = hh0 + dy;
            if ((unsigned)hh >= (unsigned)NH) continue;
#pragma unroll
            for (int dx = -3; dx <= 3; dx++) {
                int ww = ww0 + dx;
                if ((unsigned)ww >= (unsigned)NW) continue;
                float wkv = bf2f(wkrow[(dy + 3) * 7 + (dx + 3)]);
                uint_t xp = *(const uint_t*)(xT + ((size_t)(p + dy * NW + dx)) * NC + 2 * lane);
                a0 = fmaf(wkv, bf2f((ushort_t)(xp & 0xffffu)), a0);
                a1 = fmaf(wkv, bf2f((ushort_t)(xp >> 16)), a1);
            }
        }
        float s = a0 + a1, sq = a0 * a0 + a1 * a1;
#pragma unroll
        for (int d = 1; d < 64; d <<= 1) {
            s  += __shfl_xor(s, d);
            sq += __shfl_xor(sq, d);
        }
        float mean = s * (1.0f / NC);
        float var = sq * (1.0f / NC) - mean * mean;
        float rstd = rsqrtf(var + LN_EPS);
        float g0 = gelu_f((a0 - mean) * rstd * l1w0 + l1b0);
        float g1 = gelu_f((a1 - mean) * rstd * l1w1 + l1b1);
        uint_t pk = (uint_t)f2bf(g0) | ((uint_t)f2bf(g1) << 16);
        *(uint_t*)(y1 + (size_t)p * NC + 2 * lane) = pk;
    }
}

// ---------------------------------------------------------------------------
// K23 (unchanged).
// ---------------------------------------------------------------------------
__global__ __launch_bounds__(256) void k23(const ushort_t* __restrict__ y1,
                                           const ushort_t* __restrict__ xT,
                                           const ushort_t* __restrict__ wcb,
                                           const ushort_t* __restrict__ wmb,
                                           const float* __restrict__ mbf,
                                           const float* __restrict__ ln2wf,
                                           const float* __restrict__ ln2bf,
                                           const float* __restrict__ ln3wf,
                                           const float* __restrict__ ln3bf,
                                           void* __restrict__ out,
                                           const int* __restrict__ flag) {
    __shared__ __align__(16) char smem[19456];
    ushort_t* ybufF = (ushort_t*)smem;
    ushort_t* xbufF = (ushort_t*)(smem + 8192);
    float*    obuf  = (float*)smem;
    float*    sred  = (float*)(smem + 16896);
    float*    sstat = (float*)(smem + 18944);

    int isf32 = flag[0];
    int t = threadIdx.x;
    int P0 = blockIdx.x * 32;

    for (int rep = 0; rep < 2; rep++) {
        int q = rep * 256 + t;
        int pl = q & 15, quad_ = (q >> 4) & 3, kb = (q >> 6) & 3, mt = (q >> 8) & 1;
        int p = mt * 16 + pl;
        int c0 = kb * 32 + quad_ * 8;
        size_t src = (size_t)(P0 + p) * NC + c0;
        int dst = ((mt * 4 + kb) * 64 + quad_ * 16 + pl) * 8;
        *(uint4*)&ybufF[dst] = *(const uint4*)&y1[src];
        *(uint4*)&xbufF[dst] = *(const uint4*)&xT[src];
    }
    __syncthreads();

    int lane = t & 63;
    int w = __builtin_amdgcn_readfirstlane(t >> 6);
    int quad = lane >> 4;
    int l16 = lane & 15;

    floatx4 accC[2][4], accM[2][4];
#pragma unroll
    for (int mt = 0; mt < 2; mt++)
#pragma unroll
        for (int nt = 0; nt < 4; nt++) {
            accC[mt][nt] = (floatx4)0.0f;
            accM[mt][nt] = (floatx4)0.0f;
        }

#pragma unroll
    for (int kb = 0; kb < 4; kb++) {
        short8 aY0 = *(const short8*)&ybufF[((0 * 4 + kb) * 64 + lane) * 8];
        short8 aY1 = *(const short8*)&ybufF[((1 * 4 + kb) * 64 + lane) * 8];
        short8 aX0 = *(const short8*)&xbufF[((0 * 4 + kb) * 64 + lane) * 8];
        short8 aX1 = *(const short8*)&xbufF[((1 * 4 + kb) * 64 + lane) * 8];
#pragma unroll
        for (int nt = 0; nt < 4; nt++) {
            int o = w * 64 + nt * 16 + l16;
            size_t boff = (size_t)o * NC + kb * 32 + quad * 8;
            short8 bc = *(const short8*)&wcb[boff];
            short8 bm = *(const short8*)&wmb[boff];
            accC[0][nt] = __builtin_amdgcn_mfma_f32_16x16x32_bf16(aY0, bc, accC[0][nt], 0, 0, 0);
            accC[1][nt] = __builtin_amdgcn_mfma_f32_16x16x32_bf16(aY1, bc, accC[1][nt], 0, 0, 0);
            accM[0][nt] = __builtin_amdgcn_mfma_f32_16x16x32_bf16(aX0, bm, accM[0][nt], 0, 0, 0);
            accM[1][nt] = __builtin_amdgcn_mfma_f32_16x16x32_bf16(aX1, bm, accM[1][nt], 0, 0, 0);
        }
    }

    float mb_[4], l2w_[4], l2b_[4], l3w_[4], l3b_[4];
#pragma unroll
    for (int nt = 0; nt < 4; nt++) {
        int o = w * 64 + nt * 16 + l16;
        mb_[nt] = mbf[o];
        l2w_[nt] = ln2wf[o]; l2b_[nt] = ln2bf[o];
        l3w_[nt] = ln3wf[o]; l3b_[nt] = ln3bf[o];
    }
#pragma unroll
    for (int mt = 0; mt < 2; mt++)
#pragma unroll
        for (int nt = 0; nt < 4; nt++)
#pragma unroll
            for (int r = 0; r < 4; r++)
                accM[mt][nt][r] += mb_[nt];

#pragma unroll
    for (int mt = 0; mt < 2; mt++) {
#pragma unroll
        for (int r = 0; r < 4; r++) {
            float s1 = 0.f, s1q = 0.f, s2 = 0.f, s2q = 0.f;
#pragma unroll
            for (int nt = 0; nt < 4; nt++) {
                float a = accC[mt][nt][r], m = accM[mt][nt][r];
                s1 += a; s1q += a * a; s2 += m; s2q += m * m;
            }
#pragma unroll
            for (int d = 1; d < 16; d <<= 1) {
                s1  += __shfl_xor(s1, d);
                s1q += __shfl_xor(s1q, d);
                s2  += __shfl_xor(s2, d);
                s2q += __shfl_xor(s2q, d);
            }
            if (l16 == 0) {
                int px = mt * 16 + quad * 4 + r;
                float* sp = sred + ((w * 32 + px) * 4);
                sp[0] = s1; sp[1] = s1q; sp[2] = s2; sp[3] = s2q;
            }
        }
    }
    __syncthreads();

    if (t < 32) {
        float a0 = 0.f, a1 = 0.f, a2 = 0.f, a3 = 0.f;
        for (int ww = 0; ww < 4; ww++) {
            const float* sp = sred + ((ww * 32 + t) * 4);
            a0 += sp[0]; a1 += sp[1]; a2 += sp[2]; a3 += sp[3];
        }
        float m1 = a0 * (1.0f / NO);
        float v1 = a1 * (1.0f / NO) - m1 * m1;
        float m2 = a2 * (1.0f / NO);
        float v2 = a3 * (1.0f / NO) - m2 * m2;
        float* st = sstat + t * 4;
        st[0] = m1; st[1] = rsqrtf(v1 + LN_EPS);
        st[2] = m2; st[3] = rsqrtf(v2 + LN_EPS);
    }
    __syncthreads();

    int batch = P0 >> 14;
    int plocal0 = P0 & 16383;
#pragma unroll
    for (int pass = 0; pass < 2; pass++) {
#pragma unroll
        for (int ntl = 0; ntl < 2; ntl++) {
            int nt = 2 * pass + ntl;
#pragma unroll
            for (int mt = 0; mt < 2; mt++) {
#pragma unroll
                for (int r = 0; r < 4; r++) {
                    int px = mt * 16 + quad * 4 + r;
                    const float* st = sstat + px * 4;
                    float v1 = (accC[mt][nt][r] - st[0]) * st[1] * l2w_[nt] + l2b_[nt];
                    float v2 = (accM[mt][nt][r] - st[2]) * st[3] * l3w_[nt] + l3b_[nt];
                    obuf[(w * 32 + ntl * 16 + l16) * 33 + px] = gelu_f(v1 + v2);
                }
            }
        }
        __syncthreads();
        for (int it = 0; it < 16; it++) {
            int idx = it * 256 + t;
            int lr = idx >> 5, px = idx & 31;
            int o = (lr >> 5) * 64 + 32 * pass + (lr & 31);
            float val = obuf[lr * 33 + px];
            size_t oi = ((size_t)(batch * NO + o) << 14) + plocal0 + px;
            if (isf32) ((float*)out)[oi] = val;
            else       ((ushort_t*)out)[oi] = f2bf(val);
        }
        __syncthreads();
    }
}

// ---------------------------------------------------------------------------
extern "C" void kernel_launch(void* const* d_in, const int* in_sizes, int n_in,
                              void* d_out, int out_size, void* d_ws, size_t ws_size,
                              hipStream_t stream) {
    const void* x      = d_in[0];
    const void* w1     = d_in[1];
    const void* b1     = d_in[2];
    const void* w2     = d_in[3];
    const void* b2     = d_in[4];
    const void* ln1w   = d_in[5];
    const void* ln1b   = d_in[6];
    const void* conv_w = d_in[7];
    const void* ln2w   = d_in[8];
    const void* ln2b   = d_in[9];
    const void* map_w  = d_in[10];
    const void* map_b  = d_in[11];
    const void* ln3w   = d_in[12];
    const void* ln3b   = d_in[13];

    char* ws = (char*)d_ws;
    ushort_t* xT    = (ushort_t*)(ws);                  // 16,777,216 B
    ushort_t* y1    = (ushort_t*)(ws + 16777216);       // 16,777,216 B
    ushort_t* wcb   = (ushort_t*)(ws + 33554432);       //  65,536 B
    ushort_t* wmb   = (ushort_t*)(ws + 33619968);       //  65,536 B
    ushort_t* w1b   = (ushort_t*)(ws + 33685504);       //   8,192 B
    ushort_t* w2b   = (ushort_t*)(ws + 33693696);       //  25,600 B
    float*    b1f   = (float*)(ws + 33719296);
    float*    b2f   = (float*)(ws + 33719424);
    float*    ln1wf = (float*)(ws + 33721024);
    float*    ln1bf = (float*)(ws + 33721536);
    float*    mbf   = (float*)(ws + 33722048);
    float*    ln2wf = (float*)(ws + 33723072);
    float*    ln2bf = (float*)(ws + 33724096);
    float*    ln3wf = (float*)(ws + 33725120);
    float*    ln3bf = (float*)(ws + 33726144);
    int*      flag  = (int*)(ws + 33727168);
    const size_t NEED_SMALL = 33727184;
    ushort_t* wkT   = (ushort_t*)(ws + 33727232);       // 52,428,800 B
    const size_t NEED_BIG = 33727232 + (size_t)NKP * NPIX * 2;   // ~86.2 MB

    if (ws_size < NEED_SMALL) {
        int nwords = out_size / 2;
        ksentinel<<<(nwords + 255) / 256, 256, 0, stream>>>((uint_t*)d_out, nwords);
        return;
    }

    kdetect<<<1, 64, 0, stream>>>((const uint_t*)x, flag);
    kprep<<<128, 256, 0, stream>>>(w1, w2, conv_w, map_w, b1, b2, ln1w, ln1b,
                                   ln2w, ln2b, map_b, ln3w, ln3b, flag,
                                   w1b, w2b, wcb, wmb, b1f, b2f, ln1wf, ln1bf,
                                   ln2wf, ln2bf, mbf, ln3wf, ln3bf);
    ktrans<<<dim3(8, 128, 4), 256, 0, stream>>>(x, xT, flag);

    if (ws_size >= NEED_BIG) {
        k1a<<<1024, 256, 0, stream>>>(xT, w1b, b1f, w2b, b2f, wkT);
        k1b<<<1024, 512, 0, stream>>>(xT, wkT, ln1wf, ln1bf, y1);
    } else {
        k1_fused<<<dim3(16, 64, 4), 64, 0, stream>>>(xT, w1b, b1f, w2b, b2f,
                                                     ln1wf, ln1bf, y1);
    }

    k23<<<NPIX / 32, 256, 0, stream>>>(y1, xT, wcb, wmb, mbf,
                                       ln2wf, ln2bf, ln3wf, ln3bf, d_out, flag);
}

// Round 9
// 246.682 us; speedup vs baseline: 4.0916x; 1.0642x over previous
//
#include <hip/hip_runtime.h>

typedef unsigned short ushort_t;
typedef unsigned int uint_t;

#define NB 4
#define NC 128
#define NH 128
#define NW 128
#define NPIX 65536   // NB*NH*NW
#define NMID 32
#define NKK 49
#define NK 392
#define NKP 400      // NK padded to 25 n-tiles of 16
#define NO 256
#define LN_EPS 1e-6f

typedef __attribute__((ext_vector_type(8))) short short8;
typedef __attribute__((ext_vector_type(4))) float floatx4;

__device__ __forceinline__ float bf2f(ushort_t u) {
    union { uint_t i; float f; } v; v.i = ((uint_t)u) << 16; return v.f;
}
__device__ __forceinline__ float bf2f_lo(uint_t u) {
    union { uint_t i; float f; } v; v.i = u << 16; return v.f;
}
__device__ __forceinline__ float bf2f_hi(uint_t u) {
    union { uint_t i; float f; } v; v.i = u & 0xffff0000u; return v.f;
}
__device__ __forceinline__ ushort_t f2bf(float f) {
    union { float f; uint_t i; } v; v.f = f;
    uint_t x = v.i;
    uint_t r = (x + 0x7FFFu + ((x >> 16) & 1u)) >> 16;
    return (ushort_t)r;
}
__device__ __forceinline__ float gelu_f(float x) {
    return 0.5f * x * (1.0f + erff(x * 0.70710678118654752f));
}
__device__ __forceinline__ float ldin(const void* p, int i, int isf32) {
    return isf32 ? ((const float*)p)[i] : bf2f(((const ushort_t*)p)[i]);
}

// ---------------------------------------------------------------------------
__global__ void kdetect(const uint_t* __restrict__ xw, int* __restrict__ flag) {
    int lane = threadIdx.x;
    int cnt = 0;
    for (int j = 0; j < 8; j++) {
        uint_t w = xw[lane * 8 + j];
        uint_t e = (w >> 7) & 0xffu;
        if (e >= 110u && e <= 135u) cnt++;
    }
    for (int d = 1; d < 64; d <<= 1) cnt += __shfl_xor(cnt, d);
    if (lane == 0) flag[0] = (cnt < 256) ? 1 : 0;
}

__global__ void ksentinel(uint_t* __restrict__ out, int nwords) {
    int i = blockIdx.x * 256 + threadIdx.x;
    if (i < nwords) out[i] = 0x40004000u;
}

// ---------------------------------------------------------------------------
// K0a: transpose x (B,C,H,W) -> xT (B,H,W,C) canonical bf16.
// ---------------------------------------------------------------------------
__global__ __launch_bounds__(256) void ktrans(const void* __restrict__ x,
                                              ushort_t* __restrict__ xT,
                                              const int* __restrict__ flag) {
    int isf32 = flag[0];
    int b = blockIdx.z, h = blockIdx.y;
    int wchunk = blockIdx.x & 1, cchunk = blockIdx.x >> 1;
    int w0 = wchunk << 6, c0 = cchunk << 5;
    __shared__ ushort_t tile[32][66];
    int tx = threadIdx.x & 63, ty = threadIdx.x >> 6;
    for (int r = 0; r < 32; r += 4) {
        int idx = (((b * NC + c0 + r + ty) * NH) + h) * NW + w0 + tx;
        tile[r + ty][tx] = isf32 ? f2bf(((const float*)x)[idx])
                                 : ((const ushort_t*)x)[idx];
    }
    __syncthreads();
    int cc = threadIdx.x & 31, wq = threadIdx.x >> 5;
    for (int pp = 0; pp < 64; pp += 8) {
        int wx = pp + wq;
        xT[((size_t)((b * NH + h) * NW) + w0 + wx) * NC + c0 + cc] = tile[cc][wx];
    }
}

// ---------------------------------------------------------------------------
// K0b: param prep (w1b/w2b for k1a; small vectors -> fp32).
// ---------------------------------------------------------------------------
__global__ __launch_bounds__(256) void kprep(const void* w1, const void* w2,
                                             const void* b1, const void* b2,
                                             const void* ln1w, const void* ln1b,
                                             const void* ln2w, const void* ln2b,
                                             const void* map_b,
                                             const void* ln3w, const void* ln3b,
                                             const int* __restrict__ flag,
                                             ushort_t* __restrict__ w1b,
                                             ushort_t* __restrict__ w2b,
                                             float* __restrict__ b1f,
                                             float* __restrict__ b2f,
                                             float* __restrict__ ln1wf,
                                             float* __restrict__ ln1bf,
                                             float* __restrict__ ln2wf,
                                             float* __restrict__ ln2bf,
                                             float* __restrict__ mbf,
                                             float* __restrict__ ln3wf,
                                             float* __restrict__ ln3bf) {
    int isf32 = flag[0];
    int i = blockIdx.x * 256 + threadIdx.x;
    if (i < NMID * NC) w1b[i] = f2bf(ldin(w1, i, isf32));
    if (i < NKP * NMID) w2b[i] = (i < NK * NMID) ? f2bf(ldin(w2, i, isf32))
                                                 : (ushort_t)0;
    if (i < NMID) b1f[i] = ldin(b1, i, isf32);
    if (i < NKP)  b2f[i] = (i < NK) ? ldin(b2, i, isf32) : 0.f;
    if (i < NC) { ln1wf[i] = ldin(ln1w, i, isf32); ln1bf[i] = ldin(ln1b, i, isf32); }
    if (i < NO) {
        ln2wf[i] = ldin(ln2w, i, isf32); ln2bf[i] = ldin(ln2b, i, isf32);
        mbf[i]   = ldin(map_b, i, isf32);
        ln3wf[i] = ldin(ln3w, i, isf32); ln3bf[i] = ldin(ln3b, i, isf32);
    }
}

// ---------------------------------------------------------------------------
// KFRAG: repack conv_w/map_w into per-wave MFMA-fragment order for k23:
// chunk id cid = [w:2][kb:2][br:1][nt:2][lane:6], chunk = 8 bf16 = 16 B.
// k23's B load becomes base + lane*16 -> one coalesced dwordx4 per frag.
// grid 32 x 256.
// ---------------------------------------------------------------------------
__global__ __launch_bounds__(256) void kfrag(const void* conv_w, const void* map_w,
                                             const int* __restrict__ flag,
                                             ushort_t* __restrict__ wfrag) {
    int isf32 = flag[0];
    int cid = blockIdx.x * 256 + threadIdx.x;   // [0, 8192)
    int lane = cid & 63, nt = (cid >> 6) & 3, br = (cid >> 8) & 1;
    int kb = (cid >> 9) & 3, w = (cid >> 11) & 3;
    int o = w * 64 + nt * 16 + (lane & 15);
    int ch0 = kb * 32 + (lane >> 4) * 8;
    const void* src = br ? map_w : conv_w;
    ushort_t* dst = wfrag + (size_t)cid * 8;
#pragma unroll
    for (int j = 0; j < 8; j++)
        dst[j] = f2bf(ldin(src, o * NC + ch0 + j, isf32));
}

// ---------------------------------------------------------------------------
// K1a: wk producer (unchanged). grid 1024, block 256.
// ---------------------------------------------------------------------------
__global__ __launch_bounds__(256) void k1a(const ushort_t* __restrict__ xT,
                                           const ushort_t* __restrict__ w1b,
                                           const float* __restrict__ b1f,
                                           const ushort_t* __restrict__ w2b,
                                           const float* __restrict__ b2f,
                                           ushort_t* __restrict__ wkT) {
    __shared__ ushort_t midbuf[64 * 32];
    __shared__ ushort_t wkstage[NKP * 66];

    int t = threadIdx.x;
    int lane = t & 63;
    int w = __builtin_amdgcn_readfirstlane(t >> 6);
    int l16 = lane & 15, quad = lane >> 4;
    int tileid = blockIdx.x;
    int tilex = tileid & 15, tiley = (tileid >> 4) & 15, b = tileid >> 8;
    int h0 = tiley * 8, w0 = tilex * 8;

    int lpx_a = 16 * w + l16;
    int py = lpx_a >> 3, pxx = lpx_a & 7;
    const ushort_t* abase = xT + (size_t)((b * NH + h0 + py) * NW + w0 + pxx) * NC + quad * 8;
    floatx4 am0 = (floatx4)0.f, am1 = (floatx4)0.f;
#pragma unroll
    for (int kb = 0; kb < 4; kb++) {
        short8 a   = *(const short8*)(abase + kb * 32);
        short8 b0  = *(const short8*)(w1b + (l16) * NC + kb * 32 + quad * 8);
        short8 b1v = *(const short8*)(w1b + (16 + l16) * NC + kb * 32 + quad * 8);
        am0 = __builtin_amdgcn_mfma_f32_16x16x32_bf16(a, b0, am0, 0, 0, 0);
        am1 = __builtin_amdgcn_mfma_f32_16x16x32_bf16(a, b1v, am1, 0, 0, 0);
    }
    {
        float bia0 = b1f[l16], bia1 = b1f[16 + l16];
#pragma unroll
        for (int r = 0; r < 4; r++) {
            int m = 16 * w + quad * 4 + r;
            midbuf[m * 32 + l16]      = f2bf(fmaxf(am0[r] + bia0, 0.f));
            midbuf[m * 32 + 16 + l16] = f2bf(fmaxf(am1[r] + bia1, 0.f));
        }
    }
    __syncthreads();

    short8 aM = *(const short8*)(midbuf + (16 * w + l16) * 32 + quad * 8);
#pragma unroll
    for (int nt = 0; nt < 25; nt++) {
        int n = nt * 16 + l16;
        short8 bw = *(const short8*)(w2b + n * 32 + quad * 8);
        floatx4 c = __builtin_amdgcn_mfma_f32_16x16x32_bf16(aM, bw, (floatx4)0.f, 0, 0, 0);
        float bias = b2f[n];
#pragma unroll
        for (int r = 0; r < 4; r++)
            wkstage[n * 66 + 16 * w + quad * 4 + r] = f2bf(c[r] + bias);
    }
    __syncthreads();

    int krow = t >> 5, px2 = t & 31;
    for (int it = 0; it < 50; it++) {
        int k = it * 8 + krow;
        uint_t v = *(const uint_t*)&wkstage[k * 66 + 2 * px2];
        *(uint_t*)&wkT[(size_t)k * NPIX + tileid * 64 + 2 * px2] = v;
    }
}

// ---------------------------------------------------------------------------
// K1b v3 (unchanged from round 8). grid 1024, block 512.
// ---------------------------------------------------------------------------
__global__ __launch_bounds__(512) void k1b(const ushort_t* __restrict__ xT,
                                           const ushort_t* __restrict__ wkT,
                                           const float* __restrict__ ln1wf,
                                           const float* __restrict__ ln1bf,
                                           ushort_t* __restrict__ y1) {
    __shared__ __align__(16) char smem[50432];
    uint4* x8   = (uint4*)smem;
    float* sred = (float*)smem;

    int t = threadIdx.x;
    int lane = t & 63;
    int w = __builtin_amdgcn_readfirstlane(t >> 6);
    int tileid = blockIdx.x;
    int tilex = tileid & 15, tiley = (tileid >> 4) & 15, b = tileid >> 8;
    int h0 = tiley * 8, w0 = tilex * 8;
    int py = lane >> 3, pxx = lane & 7;

    const ushort_t* wkbase = wkT + (size_t)(w * NKK) * NPIX + tileid * 64 + lane;
    uint_t wkp[25];
#pragma unroll
    for (int j = 0; j < 24; j++) {
        uint_t lo = wkbase[(size_t)(2 * j) * NPIX];
        uint_t hi = wkbase[(size_t)(2 * j + 1) * NPIX];
        wkp[j] = lo | (hi << 16);
    }
    wkp[24] = wkbase[(size_t)48 * NPIX];

    for (int it = 0; it < 7; it++) {
        int idx = it * 512 + t;
        if (idx < 3136) {
            int oct = idx & 15, hp = idx >> 4;
            int hy = hp / 14, hx = hp - hy * 14;
            int gh = h0 + hy - 3, gw = w0 + hx - 3;
            uint4 v = make_uint4(0u, 0u, 0u, 0u);
            if ((unsigned)gh < (unsigned)NH && (unsigned)gw < (unsigned)NW) {
                v = *(const uint4*)&xT[(size_t)((b * NH + gh) * NW + gw) * NC + 8 * oct];
            }
            x8[oct * 197 + hp] = v;
        }
    }
    __syncthreads();

    int base0 = py * 14 + pxx;
    float a[16];
#pragma unroll
    for (int j = 0; j < 16; j++) a[j] = 0.f;

#pragma unroll
    for (int tap = 0; tap < NKK; tap++) {
        float wkf = (tap & 1) ? bf2f((ushort_t)(wkp[tap >> 1] >> 16))
                              : bf2f((ushort_t)(wkp[tap >> 1] & 0xffffu));
        int xa = base0 + (tap / 7) * 14 + (tap % 7);
        uint4 u0 = x8[(2 * w) * 197 + xa];
        uint4 u1 = x8[(2 * w + 1) * 197 + xa];
        a[0]  = fmaf(wkf, bf2f_lo(u0.x), a[0]);
        a[1]  = fmaf(wkf, bf2f_hi(u0.x), a[1]);
        a[2]  = fmaf(wkf, bf2f_lo(u0.y), a[2]);
        a[3]  = fmaf(wkf, bf2f_hi(u0.y), a[3]);
        a[4]  = fmaf(wkf, bf2f_lo(u0.z), a[4]);
        a[5]  = fmaf(wkf, bf2f_hi(u0.z), a[5]);
        a[6]  = fmaf(wkf, bf2f_lo(u0.w), a[6]);
        a[7]  = fmaf(wkf, bf2f_hi(u0.w), a[7]);
        a[8]  = fmaf(wkf, bf2f_lo(u1.x), a[8]);
        a[9]  = fmaf(wkf, bf2f_hi(u1.x), a[9]);
        a[10] = fmaf(wkf, bf2f_lo(u1.y), a[10]);
        a[11] = fmaf(wkf, bf2f_hi(u1.y), a[11]);
        a[12] = fmaf(wkf, bf2f_lo(u1.z), a[12]);
        a[13] = fmaf(wkf, bf2f_hi(u1.z), a[13]);
        a[14] = fmaf(wkf, bf2f_lo(u1.w), a[14]);
        a[15] = fmaf(wkf, bf2f_hi(u1.w), a[15]);
    }
    __syncthreads();

    float s = 0.f, sq = 0.f;
#pragma unroll
    for (int j = 0; j < 16; j++) { s += a[j]; sq += a[j] * a[j]; }
    sred[(w * 64 + lane) * 2]     = s;
    sred[(w * 64 + lane) * 2 + 1] = sq;
    __syncthreads();
    float ts = 0.f, tq = 0.f;
#pragma unroll
    for (int r = 0; r < 8; r++) {
        ts += sred[(r * 64 + lane) * 2];
        tq += sred[(r * 64 + lane) * 2 + 1];
    }
    float mean = ts * (1.0f / NC);
    float var = tq * (1.0f / NC) - mean * mean;
    float rstd = rsqrtf(var + LN_EPS);

    int p = (b * NH + h0 + py) * NW + w0 + pxx;
    uint_t pk[8];
#pragma unroll
    for (int j = 0; j < 8; j++) {
        int c0 = 16 * w + 2 * j;
        float g0 = gelu_f((a[2 * j] - mean) * rstd * ln1wf[c0] + ln1bf[c0]);
        float g1 = gelu_f((a[2 * j + 1] - mean) * rstd * ln1wf[c0 + 1] + ln1bf[c0 + 1]);
        pk[j] = (uint_t)f2bf(g0) | ((uint_t)f2bf(g1) << 16);
    }
    uint4* dst = (uint4*)(y1 + (size_t)p * NC + 16 * w);
    dst[0] = make_uint4(pk[0], pk[1], pk[2], pk[3]);
    dst[1] = make_uint4(pk[4], pk[5], pk[6], pk[7]);
}

// ---------------------------------------------------------------------------
// K1 fused fallback — used only if ws too small for wkT.
// ---------------------------------------------------------------------------
__global__ __launch_bounds__(64) void k1_fused(const ushort_t* __restrict__ xT,
                                               const ushort_t* __restrict__ w1b,
                                               const float* __restrict__ b1f,
                                               const ushort_t* __restrict__ w2b,
                                               const float* __restrict__ b2f,
                                               const float* __restrict__ ln1wf,
                                               const float* __restrict__ ln1bf,
                                               ushort_t* __restrict__ y1) {
    __shared__ ushort_t midbuf[16 * 32];
    __shared__ ushort_t wkbuf[16 * NKP];

    int lane = threadIdx.x;
    int l16 = lane & 15, quad = lane >> 4;
    int b = blockIdx.z;
    int h0 = blockIdx.y * 2, w0 = blockIdx.x * 8;

    int Pa = (b * NH + h0 + (l16 >> 3)) * NW + w0 + (l16 & 7);
    const ushort_t* abase = xT + (size_t)Pa * NC + quad * 8;
    floatx4 am0 = (floatx4)0.f, am1 = (floatx4)0.f;
#pragma unroll
    for (int kb = 0; kb < 4; kb++) {
        short8 a   = *(const short8*)(abase + kb * 32);
        short8 b0  = *(const short8*)(w1b + (l16) * NC + kb * 32 + quad * 8);
        short8 b1v = *(const short8*)(w1b + (16 + l16) * NC + kb * 32 + quad * 8);
        am0 = __builtin_amdgcn_mfma_f32_16x16x32_bf16(a, b0, am0, 0, 0, 0);
        am1 = __builtin_amdgcn_mfma_f32_16x16x32_bf16(a, b1v, am1, 0, 0, 0);
    }
    {
        float bia0 = b1f[l16], bia1 = b1f[16 + l16];
#pragma unroll
        for (int r = 0; r < 4; r++) {
            int m = quad * 4 + r;
            midbuf[m * 32 + l16]      = f2bf(fmaxf(am0[r] + bia0, 0.f));
            midbuf[m * 32 + 16 + l16] = f2bf(fmaxf(am1[r] + bia1, 0.f));
        }
    }
    __syncthreads();

    short8 aM = *(const short8*)(midbuf + l16 * 32 + quad * 8);
#pragma unroll
    for (int nt = 0; nt < 25; nt++) {
        int n = nt * 16 + l16;
        short8 bw = *(const short8*)(w2b + n * 32 + quad * 8);
        floatx4 c = __builtin_amdgcn_mfma_f32_16x16x32_bf16(aM, bw, (floatx4)0.f, 0, 0, 0);
        float bias = b2f[n];
#pragma unroll
        for (int r = 0; r < 4; r++)
            wkbuf[(quad * 4 + r) * NKP + n] = f2bf(c[r] + bias);
    }
    __syncthreads();

    int g = lane >> 3;
    float l1w0 = ln1wf[2 * lane], l1w1 = ln1wf[2 * lane + 1];
    float l1b0 = ln1bf[2 * lane], l1b1 = ln1bf[2 * lane + 1];

    for (int i = 0; i < 16; i++) {
        int hh0 = h0 + (i >> 3), ww0 = w0 + (i & 7);
        int p = (b * NH + hh0) * NW + ww0;
        const ushort_t* wkrow = wkbuf + i * NKP + g * NKK;
        float a0 = 0.f, a1 = 0.f;
#pragma unroll
        for (int dy = -3; dy <= 3; dy++) {
            int hh = hh0 + dy;
            if ((unsigned)hh >= (unsigned)NH) continue;
#pragma unroll
            for (int dx = -3; dx <= 3; dx++) {
                int ww = ww0 + dx;
                if ((unsigned)ww >= (unsigned)NW) continue;
                float wkv = bf2f(wkrow[(dy + 3) * 7 + (dx + 3)]);
                uint_t xp = *(const uint_t*)(xT + ((size_t)(p + dy * NW + dx)) * NC + 2 * lane);
                a0 = fmaf(wkv, bf2f((ushort_t)(xp & 0xffffu)), a0);
                a1 = fmaf(wkv, bf2f((ushort_t)(xp >> 16)), a1);
            }
        }
        float s = a0 + a1, sq = a0 * a0 + a1 * a1;
#pragma unroll
        for (int d = 1; d < 64; d <<= 1) {
            s  += __shfl_xor(s, d);
            sq += __shfl_xor(sq, d);
        }
        float mean = s * (1.0f / NC);
        float var = sq * (1.0f / NC) - mean * mean;
        float rstd = rsqrtf(var + LN_EPS);
        float g0 = gelu_f((a0 - mean) * rstd * l1w0 + l1b0);
        float g1 = gelu_f((a1 - mean) * rstd * l1w1 + l1b1);
        uint_t pk = (uint_t)f2bf(g0) | ((uint_t)f2bf(g1) << 16);
        *(uint_t*)(y1 + (size_t)p * NC + 2 * lane) = pk;
    }
}

// ---------------------------------------------------------------------------
// K23 v4: barrier-free K-loop; A direct from global (L1-shared across waves),
// B from fragment-ordered wfrag (fully coalesced). Epilogue as before.
// Block 256 = 4 waves; 32 px; wave w -> o in [w*64, w*64+64), both branches.
// grid 2048.
// ---------------------------------------------------------------------------
__global__ __launch_bounds__(256) void k23(const ushort_t* __restrict__ y1,
                                           const ushort_t* __restrict__ xT,
                                           const ushort_t* __restrict__ wfrag,
                                           const float* __restrict__ mbf,
                                           const float* __restrict__ ln2wf,
                                           const float* __restrict__ ln2bf,
                                           const float* __restrict__ ln3wf,
                                           const float* __restrict__ ln3bf,
                                           void* __restrict__ out,
                                           const int* __restrict__ flag) {
    __shared__ __align__(16) char smem[19456];
    float* obuf  = (float*)smem;                 // [128][33] per pass
    float* sred  = (float*)(smem + 16896);       // [4][32][4]
    float* sstat = (float*)(smem + 18944);       // [32][4]

    int isf32 = flag[0];
    int t = threadIdx.x;
    int P0 = blockIdx.x * 32;
    int lane = t & 63;
    int w = __builtin_amdgcn_readfirstlane(t >> 6);
    int quad = lane >> 4;
    int l16 = lane & 15;

    const ushort_t* aY0p = y1 + (size_t)(P0 + l16) * NC + quad * 8;
    const ushort_t* aY1p = y1 + (size_t)(P0 + 16 + l16) * NC + quad * 8;
    const ushort_t* aX0p = xT + (size_t)(P0 + l16) * NC + quad * 8;
    const ushort_t* aX1p = xT + (size_t)(P0 + 16 + l16) * NC + quad * 8;

    floatx4 accC[2][4], accM[2][4];
#pragma unroll
    for (int mt = 0; mt < 2; mt++)
#pragma unroll
        for (int nt = 0; nt < 4; nt++) {
            accC[mt][nt] = (floatx4)0.0f;
            accM[mt][nt] = (floatx4)0.0f;
        }

#pragma unroll
    for (int kb = 0; kb < 4; kb++) {
        short8 aY0 = *(const short8*)(aY0p + kb * 32);
        short8 aY1 = *(const short8*)(aY1p + kb * 32);
        short8 aX0 = *(const short8*)(aX0p + kb * 32);
        short8 aX1 = *(const short8*)(aX1p + kb * 32);
        // frag chunk base for (w, kb, br=0, nt=0): elem off = ((w*4+kb)*8*64 + lane)*8
        const ushort_t* bC = wfrag + ((size_t)((w * 4 + kb) * 8) * 64 + lane) * 8;
        const ushort_t* bM = bC + 4 * 64 * 8;   // br=1
#pragma unroll
        for (int nt = 0; nt < 4; nt++) {
            short8 bc = *(const short8*)(bC + nt * 64 * 8);
            accC[0][nt] = __builtin_amdgcn_mfma_f32_16x16x32_bf16(aY0, bc, accC[0][nt], 0, 0, 0);
            accC[1][nt] = __builtin_amdgcn_mfma_f32_16x16x32_bf16(aY1, bc, accC[1][nt], 0, 0, 0);
        }
#pragma unroll
        for (int nt = 0; nt < 4; nt++) {
            short8 bm = *(const short8*)(bM + nt * 64 * 8);
            accM[0][nt] = __builtin_amdgcn_mfma_f32_16x16x32_bf16(aX0, bm, accM[0][nt], 0, 0, 0);
            accM[1][nt] = __builtin_amdgcn_mfma_f32_16x16x32_bf16(aX1, bm, accM[1][nt], 0, 0, 0);
        }
    }

    float mb_[4], l2w_[4], l2b_[4], l3w_[4], l3b_[4];
#pragma unroll
    for (int nt = 0; nt < 4; nt++) {
        int o = w * 64 + nt * 16 + l16;
        mb_[nt] = mbf[o];
        l2w_[nt] = ln2wf[o]; l2b_[nt] = ln2bf[o];
        l3w_[nt] = ln3wf[o]; l3b_[nt] = ln3bf[o];
    }
#pragma unroll
    for (int mt = 0; mt < 2; mt++)
#pragma unroll
        for (int nt = 0; nt < 4; nt++)
#pragma unroll
            for (int r = 0; r < 4; r++)
                accM[mt][nt][r] += mb_[nt];

#pragma unroll
    for (int mt = 0; mt < 2; mt++) {
#pragma unroll
        for (int r = 0; r < 4; r++) {
            float s1 = 0.f, s1q = 0.f, s2 = 0.f, s2q = 0.f;
#pragma unroll
            for (int nt = 0; nt < 4; nt++) {
                float a = accC[mt][nt][r], m = accM[mt][nt][r];
                s1 += a; s1q += a * a; s2 += m; s2q += m * m;
            }
#pragma unroll
            for (int d = 1; d < 16; d <<= 1) {
                s1  += __shfl_xor(s1, d);
                s1q += __shfl_xor(s1q, d);
                s2  += __shfl_xor(s2, d);
                s2q += __shfl_xor(s2q, d);
            }
            if (l16 == 0) {
                int px = mt * 16 + quad * 4 + r;
                float* sp = sred + ((w * 32 + px) * 4);
                sp[0] = s1; sp[1] = s1q; sp[2] = s2; sp[3] = s2q;
            }
        }
    }
    __syncthreads();

    if (t < 32) {
        float a0 = 0.f, a1 = 0.f, a2 = 0.f, a3 = 0.f;
        for (int ww = 0; ww < 4; ww++) {
            const float* sp = sred + ((ww * 32 + t) * 4);
            a0 += sp[0]; a1 += sp[1]; a2 += sp[2]; a3 += sp[3];
        }
        float m1 = a0 * (1.0f / NO);
        float v1 = a1 * (1.0f / NO) - m1 * m1;
        float m2 = a2 * (1.0f / NO);
        float v2 = a3 * (1.0f / NO) - m2 * m2;
        float* st = sstat + t * 4;
        st[0] = m1; st[1] = rsqrtf(v1 + LN_EPS);
        st[2] = m2; st[3] = rsqrtf(v2 + LN_EPS);
    }
    __syncthreads();

    int batch = P0 >> 14;
    int plocal0 = P0 & 16383;
#pragma unroll
    for (int pass = 0; pass < 2; pass++) {
#pragma unroll
        for (int ntl = 0; ntl < 2; ntl++) {
            int nt = 2 * pass + ntl;
#pragma unroll
            for (int mt = 0; mt < 2; mt++) {
#pragma unroll
                for (int r = 0; r < 4; r++) {
                    int px = mt * 16 + quad * 4 + r;
                    const float* st = sstat + px * 4;
                    float v1 = (accC[mt][nt][r] - st[0]) * st[1] * l2w_[nt] + l2b_[nt];
                    float v2 = (accM[mt][nt][r] - st[2]) * st[3] * l3w_[nt] + l3b_[nt];
                    obuf[(w * 32 + ntl * 16 + l16) * 33 + px] = gelu_f(v1 + v2);
                }
            }
        }
        __syncthreads();
        for (int it = 0; it < 16; it++) {
            int idx = it * 256 + t;
            int lr = idx >> 5, px = idx & 31;
            int o = (lr >> 5) * 64 + 32 * pass + (lr & 31);
            float val = obuf[lr * 33 + px];
            size_t oi = ((size_t)(batch * NO + o) << 14) + plocal0 + px;
            if (isf32) ((float*)out)[oi] = val;
            else       ((ushort_t*)out)[oi] = f2bf(val);
        }
        __syncthreads();
    }
}

// ---------------------------------------------------------------------------
extern "C" void kernel_launch(void* const* d_in, const int* in_sizes, int n_in,
                              void* d_out, int out_size, void* d_ws, size_t ws_size,
                              hipStream_t stream) {
    const void* x      = d_in[0];
    const void* w1     = d_in[1];
    const void* b1     = d_in[2];
    const void* w2     = d_in[3];
    const void* b2     = d_in[4];
    const void* ln1w   = d_in[5];
    const void* ln1b   = d_in[6];
    const void* conv_w = d_in[7];
    const void* ln2w   = d_in[8];
    const void* ln2b   = d_in[9];
    const void* map_w  = d_in[10];
    const void* map_b  = d_in[11];
    const void* ln3w   = d_in[12];
    const void* ln3b   = d_in[13];

    char* ws = (char*)d_ws;
    ushort_t* xT    = (ushort_t*)(ws);                  // 16,777,216 B
    ushort_t* y1    = (ushort_t*)(ws + 16777216);       // 16,777,216 B
    ushort_t* wfrag = (ushort_t*)(ws + 33554432);       // 131,072 B
    ushort_t* w1b   = (ushort_t*)(ws + 33685504);       //   8,192 B
    ushort_t* w2b   = (ushort_t*)(ws + 33693696);       //  25,600 B
    float*    b1f   = (float*)(ws + 33719296);
    float*    b2f   = (float*)(ws + 33719424);
    float*    ln1wf = (float*)(ws + 33721024);
    float*    ln1bf = (float*)(ws + 33721536);
    float*    mbf   = (float*)(ws + 33722048);
    float*    ln2wf = (float*)(ws + 33723072);
    float*    ln2bf = (float*)(ws + 33724096);
    float*    ln3wf = (float*)(ws + 33725120);
    float*    ln3bf = (float*)(ws + 33726144);
    int*      flag  = (int*)(ws + 33727168);
    const size_t NEED_SMALL = 33727184;
    ushort_t* wkT   = (ushort_t*)(ws + 33727232);       // 52,428,800 B
    const size_t NEED_BIG = 33727232 + (size_t)NKP * NPIX * 2;   // ~86.2 MB

    if (ws_size < NEED_SMALL) {
        int nwords = out_size / 2;
        ksentinel<<<(nwords + 255) / 256, 256, 0, stream>>>((uint_t*)d_out, nwords);
        return;
    }

    kdetect<<<1, 64, 0, stream>>>((const uint_t*)x, flag);
    kprep<<<128, 256, 0, stream>>>(w1, w2, b1, b2, ln1w, ln1b,
                                   ln2w, ln2b, map_b, ln3w, ln3b, flag,
                                   w1b, w2b, b1f, b2f, ln1wf, ln1bf,
                                   ln2wf, ln2bf, mbf, ln3wf, ln3bf);
    kfrag<<<32, 256, 0, stream>>>(conv_w, map_w, flag, wfrag);
    ktrans<<<dim3(8, 128, 4), 256, 0, stream>>>(x, xT, flag);

    if (ws_size >= NEED_BIG) {
        k1a<<<1024, 256, 0, stream>>>(xT, w1b, b1f, w2b, b2f, wkT);
        k1b<<<1024, 512, 0, stream>>>(xT, wkT, ln1wf, ln1bf, y1);
    } else {
        k1_fused<<<dim3(16, 64, 4), 64, 0, stream>>>(xT, w1b, b1f, w2b, b2f,
                                                     ln1wf, ln1bf, y1);
    }

    k23<<<NPIX / 32, 256, 0, stream>>>(y1, xT, wfrag, mbf,
                                       ln2wf, ln2bf, ln3wf, ln3bf, d_out, flag);
}